// Round 5
// baseline (565.777 us; speedup 1.0000x reference)
//
#include <hip/hip_runtime.h>
#include <math.h>

#define BB 4
#define SS 1024
#define EE 1024
#define HH 16
#define DD 64
#define RR 129
#define PRELW 130   // prel row stride (ushorts): 260B rows, 4B-aligned, bank-clean

typedef __attribute__((ext_vector_type(4))) float f32x4;
typedef __attribute__((ext_vector_type(8))) short bf8;   // 8 bf16 = 4 VGPR (MFMA A/B frag)
typedef __attribute__((ext_vector_type(4))) short s4v;   // 4 bf16 = 8B

#define MFMA(a, b, c) __builtin_amdgcn_mfma_f32_16x16x32_bf16(a, b, c, 0, 0, 0)

__device__ __forceinline__ float bf2f(unsigned short u) {
    return __uint_as_float(((unsigned)u) << 16);
}
__device__ __forceinline__ unsigned short f2bf(float x) {  // RNE
    unsigned u = __float_as_uint(x);
    return (unsigned short)((u + 0x7fffu + ((u >> 16) & 1u)) >> 16);
}

// ---------------------------------------------------------------------------
// Weight transpose+split: W[K][N] fp32 -> Wt_hi/lo[N][K] bf16.
// ---------------------------------------------------------------------------
__global__ __launch_bounds__(256, 4)
void wtrans_kernel(const float* __restrict__ Wq, const float* __restrict__ Wk,
                   const float* __restrict__ Wv, const float* __restrict__ Wo,
                   unsigned short* __restrict__ wt_hi, unsigned short* __restrict__ wt_lo)
{
    __shared__ float T[64][65];
    const int w = blockIdx.z;
    const float* W = w == 0 ? Wq : (w == 1 ? Wk : (w == 2 ? Wv : Wo));
    const int n0 = blockIdx.x * 64, k0 = blockIdx.y * 64;
    const int tid = threadIdx.x;
#pragma unroll
    for (int i = 0; i < 4; ++i) {
        int c = tid + 256 * i; int r = c >> 4, c4 = c & 15;
        f32x4 v = *(const f32x4*)(W + (size_t)(k0 + r) * EE + n0 + c4 * 4);
        T[r][c4 * 4 + 0] = v.x; T[r][c4 * 4 + 1] = v.y;
        T[r][c4 * 4 + 2] = v.z; T[r][c4 * 4 + 3] = v.w;
    }
    __syncthreads();
#pragma unroll
    for (int i = 0; i < 4; ++i) {
        int c = tid + 256 * i; int r = c >> 4, c4 = c & 15;   // r = n_local, c4 = k group
        float x0 = T[c4 * 4 + 0][r], x1 = T[c4 * 4 + 1][r];
        float x2 = T[c4 * 4 + 2][r], x3 = T[c4 * 4 + 3][r];
        unsigned short h0 = f2bf(x0), h1 = f2bf(x1), h2 = f2bf(x2), h3 = f2bf(x3);
        unsigned short l0 = f2bf(x0 - bf2f(h0)), l1 = f2bf(x1 - bf2f(h1));
        unsigned short l2 = f2bf(x2 - bf2f(h2)), l3 = f2bf(x3 - bf2f(h3));
        size_t o = (size_t)w * 1048576 + (size_t)(n0 + r) * 1024 + k0 + c4 * 4;
        *(s4v*)&wt_hi[o] = (s4v){(short)h0, (short)h1, (short)h2, (short)h3};
        *(s4v*)&wt_lo[o] = (s4v){(short)l0, (short)l1, (short)l2, (short)l3};
    }
}

// ---------------------------------------------------------------------------
// Pack attn_mask int32 -> bitmask u64 words. One thread per word (64 ints).
// ---------------------------------------------------------------------------
__global__ __launch_bounds__(256)
void maskbits_kernel(const int* __restrict__ mask, unsigned long long* __restrict__ mb)
{
    const int w = blockIdx.x * 256 + threadIdx.x;   // 65536 words
    const int* p = mask + (size_t)w * 64;
    unsigned long long bits = 0;
#pragma unroll
    for (int i = 0; i < 16; ++i) {
        int4 v = *(const int4*)(p + i * 4);
        bits |= (unsigned long long)(v.x != 0) << (i * 4 + 0);
        bits |= (unsigned long long)(v.y != 0) << (i * 4 + 1);
        bits |= (unsigned long long)(v.z != 0) << (i * 4 + 2);
        bits |= (unsigned long long)(v.w != 0) << (i * 4 + 3);
    }
    mb[w] = bits;
}

// ---------------------------------------------------------------------------
// Split-bf16 MFMA GEMM body (projections / out-proj).
// ---------------------------------------------------------------------------
template<int ASRC, int EPI>
__device__ __forceinline__ void gemm_body(
    const float* __restrict__ Af,
    const unsigned short* __restrict__ Ah_g, const unsigned short* __restrict__ Al_g,
    const unsigned short* __restrict__ Bh_g, const unsigned short* __restrict__ Bl_g,
    const float* __restrict__ bias,
    float* __restrict__ Yf, unsigned short* __restrict__ Yh, unsigned short* __restrict__ Yl,
    unsigned short* As_h, unsigned short* As_l, unsigned short* Bs_h, unsigned short* Bs_l,
    int m0, int n0)
{
    const int tid = threadIdx.x, lane = tid & 63, wid = tid >> 6;
    const int wm = (wid >> 1) * 64, wn = (wid & 1) * 64;
    f32x4 zero4 = {0.f, 0.f, 0.f, 0.f};
    f32x4 acc[4][4];
#pragma unroll
    for (int a = 0; a < 4; ++a)
#pragma unroll
        for (int b = 0; b < 4; ++b) acc[a][b] = zero4;

    for (int kt = 0; kt < 1024; kt += 64) {
        __syncthreads();
        if (ASRC == 0) {
#pragma unroll
            for (int i = 0; i < 8; ++i) {
                int c = tid + 256 * i; int r = c >> 4, c4 = c & 15;
                f32x4 v = *(const f32x4*)(Af + (size_t)(m0 + r) * 1024 + kt + c4 * 4);
                unsigned short h0 = f2bf(v.x), h1 = f2bf(v.y), h2 = f2bf(v.z), h3 = f2bf(v.w);
                unsigned short l0 = f2bf(v.x - bf2f(h0)), l1 = f2bf(v.y - bf2f(h1));
                unsigned short l2 = f2bf(v.z - bf2f(h2)), l3 = f2bf(v.w - bf2f(h3));
                int off = r * 64 + (((c4 >> 1) ^ (r & 7)) * 8) + (c4 & 1) * 4;
                *(s4v*)&As_h[off] = (s4v){(short)h0, (short)h1, (short)h2, (short)h3};
                *(s4v*)&As_l[off] = (s4v){(short)l0, (short)l1, (short)l2, (short)l3};
            }
        } else {
#pragma unroll
            for (int i = 0; i < 4; ++i) {
                int c = tid + 256 * i; int r = c >> 3, cc = c & 7;
                int off = r * 64 + ((cc ^ (r & 7)) * 8);
                *(bf8*)&As_h[off] = *(const bf8*)(Ah_g + (size_t)(m0 + r) * 1024 + kt + cc * 8);
                *(bf8*)&As_l[off] = *(const bf8*)(Al_g + (size_t)(m0 + r) * 1024 + kt + cc * 8);
            }
        }
#pragma unroll
        for (int i = 0; i < 4; ++i) {
            int c = tid + 256 * i; int r = c >> 3, cc = c & 7;
            int off = r * 64 + ((cc ^ (r & 7)) * 8);
            *(bf8*)&Bs_h[off] = *(const bf8*)(Bh_g + (size_t)(n0 + r) * 1024 + kt + cc * 8);
            *(bf8*)&Bs_l[off] = *(const bf8*)(Bl_g + (size_t)(n0 + r) * 1024 + kt + cc * 8);
        }
        __syncthreads();
#pragma unroll
        for (int ks = 0; ks < 2; ++ks) {
            bf8 ah[4], al[4], bh[4], bl[4];
#pragma unroll
            for (int f = 0; f < 4; ++f) {
                int ra = wm + f * 16 + (lane & 15);
                int ca = (ks * 4 + (lane >> 4)) ^ (ra & 7);
                ah[f] = *(const bf8*)&As_h[ra * 64 + ca * 8];
                al[f] = *(const bf8*)&As_l[ra * 64 + ca * 8];
                int rb = wn + f * 16 + (lane & 15);
                int cb = (ks * 4 + (lane >> 4)) ^ (rb & 7);
                bh[f] = *(const bf8*)&Bs_h[rb * 64 + cb * 8];
                bl[f] = *(const bf8*)&Bs_l[rb * 64 + cb * 8];
            }
#pragma unroll
            for (int fi = 0; fi < 4; ++fi)
#pragma unroll
                for (int fj = 0; fj < 4; ++fj) {
                    acc[fi][fj] = MFMA(ah[fi], bh[fj], acc[fi][fj]);
                    acc[fi][fj] = MFMA(al[fi], bh[fj], acc[fi][fj]);
                    acc[fi][fj] = MFMA(ah[fi], bl[fj], acc[fi][fj]);
                }
        }
    }
    // epilogue: C/D layout (m89): col = lane&15, row = (lane>>4)*4 + reg
#pragma unroll
    for (int fi = 0; fi < 4; ++fi)
#pragma unroll
        for (int fj = 0; fj < 4; ++fj)
#pragma unroll
            for (int rg = 0; rg < 4; ++rg) {
                int m = m0 + wm + fi * 16 + ((lane >> 4) << 2) + rg;
                int n = n0 + wn + fj * 16 + (lane & 15);
                float val = acc[fi][fj][rg] + bias[n];
                if (EPI == 0) {
                    int b = m >> 10, s = m & 1023, h = n >> 6, d = n & 63;
                    size_t o = (((size_t)(b * 16 + h)) * 1024 + s) * 64 + d;
                    unsigned short hv = f2bf(val);
                    unsigned short lv = f2bf(val - bf2f(hv));
                    Yh[o] = hv; Yl[o] = lv;
                } else {
                    Yf[(size_t)m * 1024 + n] = val;
                }
            }
}

__global__ __launch_bounds__(256, 2)
void proj_qkv_kernel(const float* __restrict__ q_in, const float* __restrict__ k_in,
                     const float* __restrict__ v_in,
                     const unsigned short* __restrict__ wt_hi, const unsigned short* __restrict__ wt_lo,
                     const float* __restrict__ bq, const float* __restrict__ bk,
                     const float* __restrict__ bv,
                     unsigned short* qh_hi, unsigned short* qh_lo,
                     unsigned short* kh_hi, unsigned short* kh_lo,
                     unsigned short* vh_hi, unsigned short* vh_lo)
{
    __shared__ __align__(16) unsigned short As_h[128 * 64], As_l[128 * 64];
    __shared__ __align__(16) unsigned short Bs_h[128 * 64], Bs_l[128 * 64];
    const int z = blockIdx.z;
    const float* X = z == 0 ? q_in : (z == 1 ? k_in : v_in);
    const float* bias = z == 0 ? bq : (z == 1 ? bk : bv);
    unsigned short* Yh = z == 0 ? qh_hi : (z == 1 ? kh_hi : vh_hi);
    unsigned short* Yl = z == 0 ? qh_lo : (z == 1 ? kh_lo : vh_lo);
    gemm_body<0, 0>(X, nullptr, nullptr,
                    wt_hi + (size_t)z * 1048576, wt_lo + (size_t)z * 1048576,
                    bias, nullptr, Yh, Yl, As_h, As_l, Bs_h, Bs_l,
                    blockIdx.x * 128, blockIdx.y * 128);
}

__global__ __launch_bounds__(256, 2)
void outproj_kernel(const unsigned short* __restrict__ ctx_hi, const unsigned short* __restrict__ ctx_lo,
                    const unsigned short* __restrict__ wo_hi, const unsigned short* __restrict__ wo_lo,
                    const float* __restrict__ bo, float* __restrict__ out)
{
    __shared__ __align__(16) unsigned short As_h[128 * 64], As_l[128 * 64];
    __shared__ __align__(16) unsigned short Bs_h[128 * 64], Bs_l[128 * 64];
    gemm_body<1, 1>(nullptr, ctx_hi, ctx_lo, wo_hi, wo_lo, bo, out, nullptr, nullptr,
                    As_h, As_l, Bs_h, Bs_l, blockIdx.x * 128, blockIdx.y * 128);
}

// ---------------------------------------------------------------------------
// V transpose: vh[bh][s][d] (ushort) -> vt[bh][d][s]. z: 0=hi,1=lo buffers.
// ---------------------------------------------------------------------------
__global__ __launch_bounds__(256, 4)
void vtrans_kernel(const unsigned short* __restrict__ vh_hi, const unsigned short* __restrict__ vh_lo,
                   unsigned short* __restrict__ vt_hi, unsigned short* __restrict__ vt_lo)
{
    __shared__ unsigned short T[64][72];
    const unsigned short* src = blockIdx.z ? vh_lo : vh_hi;
    unsigned short* dst = blockIdx.z ? vt_lo : vt_hi;
    const int st = blockIdx.x * 64, bh = blockIdx.y, tid = threadIdx.x;
#pragma unroll
    for (int i = 0; i < 4; ++i) {
        int c = tid + 256 * i; int r = c >> 4, d4 = c & 15;
        s4v v = *(const s4v*)(src + ((size_t)bh * 1024 + st + r) * 64 + d4 * 4);
        T[r][d4 * 4 + 0] = (unsigned short)v.x; T[r][d4 * 4 + 1] = (unsigned short)v.y;
        T[r][d4 * 4 + 2] = (unsigned short)v.z; T[r][d4 * 4 + 3] = (unsigned short)v.w;
    }
    __syncthreads();
#pragma unroll
    for (int i = 0; i < 4; ++i) {
        int c = tid + 256 * i; int r = c >> 4, s4_ = c & 15;  // r = d row
        s4v o = {(short)T[s4_ * 4 + 0][r], (short)T[s4_ * 4 + 1][r],
                 (short)T[s4_ * 4 + 2][r], (short)T[s4_ * 4 + 3][r]};
        *(s4v*)(dst + ((size_t)bh * 64 + r) * 1024 + st + s4_ * 4) = o;
    }
}

// ---------------------------------------------------------------------------
// prel[row][r] = q_hi[row,:64] . emb[r,:64]  (row = bh*1024+s), bf16 out,
// global row stride PRELW=130.
// ---------------------------------------------------------------------------
__global__ __launch_bounds__(256, 2)
void relproj_kernel(const unsigned short* __restrict__ qh_hi, const float* __restrict__ emb,
                    unsigned short* __restrict__ prel)
{
    __shared__ float se[RR][68];
    __shared__ float sq[128][68];
    const int tid = threadIdx.x;
    const size_t row0 = (size_t)blockIdx.x * 128;
    for (int i = tid; i < RR * 64; i += 256) { int r = i >> 6, d = i & 63; se[r][d] = emb[i]; }
#pragma unroll
    for (int i = 0; i < 8; ++i) {
        int c = tid + 256 * i; int r = c >> 4, d4 = c & 15;
        s4v v = *(const s4v*)(qh_hi + (row0 + r) * 64 + d4 * 4);
        sq[r][d4 * 4 + 0] = bf2f((unsigned short)v.x);
        sq[r][d4 * 4 + 1] = bf2f((unsigned short)v.y);
        sq[r][d4 * 4 + 2] = bf2f((unsigned short)v.z);
        sq[r][d4 * 4 + 3] = bf2f((unsigned short)v.w);
    }
    __syncthreads();
    for (int idx = tid; idx < 128 * RR; idx += 256) {
        int r = idx / RR, c = idx - r * RR;
        const float* a = sq[r];
        const float* b = se[c];
        float s = 0.f;
#pragma unroll
        for (int d = 0; d < 64; ++d) s = fmaf(a[d], b[d], s);
        prel[(row0 + r) * PRELW + c] = f2bf(s);
    }
}

// ---------------------------------------------------------------------------
// Scores: swapped-operand MFMA (A=K rows -> C row=j, B=Q rows -> C col=i).
// Raw s = QK^T/8 + relbias (masked -1e30) written fp32 (float4 stores).
// Online row max/sum -> rowm/rowsum. prel in LDS; mask via bitmask; Q frags
// hoisted to registers.
// ---------------------------------------------------------------------------
__global__ __launch_bounds__(256, 2)
void scores_kernel(const unsigned short* __restrict__ qh_hi, const unsigned short* __restrict__ qh_lo,
                   const unsigned short* __restrict__ kh_hi, const unsigned short* __restrict__ kh_lo,
                   const unsigned short* __restrict__ prel, const unsigned long long* __restrict__ mb,
                   float* __restrict__ attn, float* __restrict__ rowm, float* __restrict__ rowsum)
{
    __shared__ __align__(16) unsigned short Sh[128 * 64], Sl[128 * 64];  // Q once, then K tiles
    __shared__ __align__(16) unsigned short Pr[128 * PRELW];
    __shared__ float Sm[2][128], Ss[2][128];
    const int tid = threadIdx.x, lane = tid & 63, wid = tid >> 6;
    const int wi = wid >> 1, wj = wid & 1;
    const int g = lane >> 4, li = lane & 15;
    const int i0 = blockIdx.x * 128, bh = blockIdx.y, b = bh >> 4;

    // stage Q tile (swizzled rows = i)
    const unsigned short* qbh = qh_hi + ((size_t)bh * 1024 + i0) * 64;
    const unsigned short* qbl = qh_lo + ((size_t)bh * 1024 + i0) * 64;
#pragma unroll
    for (int i = 0; i < 4; ++i) {
        int c = tid + 256 * i; int r = c >> 3, cc = c & 7;
        int off = r * 64 + ((cc ^ (r & 7)) * 8);
        *(bf8*)&Sh[off] = *(const bf8*)(qbh + r * 64 + cc * 8);
        *(bf8*)&Sl[off] = *(const bf8*)(qbl + r * 64 + cc * 8);
    }
    // stage prel rows: flat contiguous copy (128 rows x 65 u32)
    {
        const unsigned* src = (const unsigned*)(prel + ((size_t)bh * 1024 + i0) * PRELW);
        unsigned* dst = (unsigned*)Pr;
        for (int idx = tid; idx < 128 * (PRELW / 2); idx += 256) dst[idx] = src[idx];
    }
    __syncthreads();
    // Q fragments to registers (loop-invariant B operand)
    bf8 qfh[4][2], qfl[4][2];
#pragma unroll
    for (int fi = 0; fi < 4; ++fi)
#pragma unroll
        for (int ks = 0; ks < 2; ++ks) {
            int rb = wi * 64 + fi * 16 + li;
            int cb = (ks * 4 + g) ^ (rb & 7);
            qfh[fi][ks] = *(const bf8*)&Sh[rb * 64 + cb * 8];
            qfl[fi][ks] = *(const bf8*)&Sl[rb * 64 + cb * 8];
        }

    float rm[4], rs[4];
#pragma unroll
    for (int i = 0; i < 4; ++i) { rm[i] = -3.0e38f; rs[i] = 0.f; }

    for (int jt = 0; jt < 8; ++jt) {
        __syncthreads();   // guards Q-frag reads (jt=0) / prior-tile frag reads
        const unsigned short* kbh = kh_hi + ((size_t)bh * 1024 + jt * 128) * 64;
        const unsigned short* kbl = kh_lo + ((size_t)bh * 1024 + jt * 128) * 64;
#pragma unroll
        for (int i = 0; i < 4; ++i) {
            int c = tid + 256 * i; int r = c >> 3, cc = c & 7;
            int off = r * 64 + ((cc ^ (r & 7)) * 8);
            *(bf8*)&Sh[off] = *(const bf8*)(kbh + r * 64 + cc * 8);
            *(bf8*)&Sl[off] = *(const bf8*)(kbl + r * 64 + cc * 8);
        }
        __syncthreads();
        f32x4 zero4 = {0.f, 0.f, 0.f, 0.f};
        f32x4 acc[4][4];  // [fj][fi]
#pragma unroll
        for (int a = 0; a < 4; ++a)
#pragma unroll
            for (int c = 0; c < 4; ++c) acc[a][c] = zero4;
#pragma unroll
        for (int ks = 0; ks < 2; ++ks) {
            bf8 kfh[4], kfl[4];
#pragma unroll
            for (int fj = 0; fj < 4; ++fj) {
                int ra = wj * 64 + fj * 16 + li;
                int ca = (ks * 4 + g) ^ (ra & 7);
                kfh[fj] = *(const bf8*)&Sh[ra * 64 + ca * 8];
                kfl[fj] = *(const bf8*)&Sl[ra * 64 + ca * 8];
            }
#pragma unroll
            for (int fj = 0; fj < 4; ++fj)
#pragma unroll
                for (int fi = 0; fi < 4; ++fi) {
                    acc[fj][fi] = MFMA(kfh[fj], qfh[fi][ks], acc[fj][fi]);
                    acc[fj][fi] = MFMA(kfl[fj], qfh[fi][ks], acc[fj][fi]);
                    acc[fj][fi] = MFMA(kfh[fj], qfl[fi][ks], acc[fj][fi]);
                }
        }
        // epilogue: bias from LDS, mask from bitmask, float4 raw stores, stats
#pragma unroll
        for (int fi = 0; fi < 4; ++fi) {
            const int rowL = wi * 64 + fi * 16 + li;
            const int ii = i0 + rowL;
            const unsigned long long mw = mb[((size_t)b * 1024 + ii) * 16 + jt * 2 + wj];
            float p16[4][4];
            float tmax = -3.0e38f;
#pragma unroll
            for (int fj = 0; fj < 4; ++fj)
#pragma unroll
                for (int rg = 0; rg < 4; ++rg) {
                    int jloc = fj * 16 + g * 4 + rg;
                    int jj = jt * 128 + wj * 64 + jloc;
                    int dd = ii - jj; dd = dd < -64 ? -64 : (dd > 64 ? 64 : dd);
                    float s = acc[fj][fi][rg] * 0.125f + bf2f(Pr[rowL * PRELW + dd + 64]);
                    if (!((mw >> jloc) & 1ull)) s = -1.0e30f;
                    p16[fj][rg] = s;
                    tmax = fmaxf(tmax, s);
                }
            tmax = fmaxf(tmax, __shfl_xor(tmax, 16, 64));
            tmax = fmaxf(tmax, __shfl_xor(tmax, 32, 64));
            float nm = fmaxf(rm[fi], tmax);
            float ps = 0.f;
#pragma unroll
            for (int fj = 0; fj < 4; ++fj)
#pragma unroll
                for (int rg = 0; rg < 4; ++rg) ps += __expf(p16[fj][rg] - nm);
            ps += __shfl_xor(ps, 16, 64);
            ps += __shfl_xor(ps, 32, 64);
            rs[fi] = rs[fi] * __expf(rm[fi] - nm) + ps;
            rm[fi] = nm;
            float* arow = attn + ((size_t)bh * 1024 + ii) * 1024 + jt * 128 + wj * 64 + g * 4;
#pragma unroll
            for (int fj = 0; fj < 4; ++fj) {
                f32x4 st = {p16[fj][0], p16[fj][1], p16[fj][2], p16[fj][3]};
                *(f32x4*)(arow + fj * 16) = st;
            }
        }
    }
    // combine the two j-half waves per i-row
#pragma unroll
    for (int fi = 0; fi < 4; ++fi) {
        if (lane < 16) {
            Sm[wj][wi * 64 + fi * 16 + li] = rm[fi];
            Ss[wj][wi * 64 + fi * 16 + li] = rs[fi];
        }
    }
    __syncthreads();
    if (tid < 128) {
        float m0_ = Sm[0][tid], m1_ = Sm[1][tid];
        float mm = fmaxf(m0_, m1_);
        float ss = Ss[0][tid] * __expf(m0_ - mm) + Ss[1][tid] * __expf(m1_ - mm);
        rowm[(size_t)bh * 1024 + i0 + tid] = mm;
        rowsum[(size_t)bh * 1024 + i0 + tid] = ss;
    }
}

// ---------------------------------------------------------------------------
// PV — barrier-free, LDS-free, latency-hidden. Each wave owns 16 i-rows
// (one A-frag row set) x all 64 d. Grid (16,64) = 1024 blocks = 4 blocks/CU.
// Lane (g,li): row li of the wave's set, j-chunk cols jc*32 + g*8 .. +8.
// Register double-buffer on the attn reads; V frags loaded before the exp
// VALU block so latency hides under it.
// ---------------------------------------------------------------------------
__global__ __launch_bounds__(256, 4)
void pv_kernel(float* __restrict__ attn,
               const unsigned short* __restrict__ vt_hi, const unsigned short* __restrict__ vt_lo,
               const float* __restrict__ rowm, const float* __restrict__ rowsum,
               unsigned short* __restrict__ ctx_hi, unsigned short* __restrict__ ctx_lo)
{
    const int tid = threadIdx.x, lane = tid & 63, wid = tid >> 6;
    const int g = lane >> 4, li = lane & 15;
    const int i0 = blockIdx.x * 64, bh = blockIdx.y;
    const int row = i0 + wid * 16 + li;

    const float mm = rowm[(size_t)bh * 1024 + row];
    const float iv = 1.f / rowsum[(size_t)bh * 1024 + row];
    float* ap = attn + ((size_t)bh * 1024 + row) * 1024 + g * 8;
    const unsigned short* vbh = vt_hi + (size_t)bh * 65536 + (size_t)li * 1024 + g * 8;
    const unsigned short* vbl = vt_lo + (size_t)bh * 65536 + (size_t)li * 1024 + g * 8;

    f32x4 zero4 = {0.f, 0.f, 0.f, 0.f};
    f32x4 acc[4] = {zero4, zero4, zero4, zero4};

    f32x4 c0 = *(const f32x4*)ap;
    f32x4 c1 = *(const f32x4*)(ap + 4);
    for (int jc = 0; jc < 32; ++jc) {
        // prefetch next attn chunk (clamped address; value unused at jc=31)
        const int nidx = (jc < 31 ? jc + 1 : 0) * 32;
        f32x4 n0 = *(const f32x4*)(ap + nidx);
        f32x4 n1 = *(const f32x4*)(ap + nidx + 4);
        // V fragments for this chunk (issue before the exp VALU block)
        bf8 vh_[4], vl_[4];
#pragma unroll
        for (int fj = 0; fj < 4; ++fj) {
            vh_[fj] = *(const bf8*)(vbh + (size_t)fj * 16384 + jc * 32);
            vl_[fj] = *(const bf8*)(vbl + (size_t)fj * 16384 + jc * 32);
        }
        // normalize, store final weights, pack hi/lo A-frags
        float p0 = __expf(c0.x - mm) * iv, p1 = __expf(c0.y - mm) * iv;
        float p2 = __expf(c0.z - mm) * iv, p3 = __expf(c0.w - mm) * iv;
        float p4 = __expf(c1.x - mm) * iv, p5 = __expf(c1.y - mm) * iv;
        float p6 = __expf(c1.z - mm) * iv, p7 = __expf(c1.w - mm) * iv;
        f32x4 o0 = {p0, p1, p2, p3}, o1 = {p4, p5, p6, p7};
        *(f32x4*)(ap + jc * 32) = o0;            // final attention weights
        *(f32x4*)(ap + jc * 32 + 4) = o1;
        unsigned short h0 = f2bf(p0), h1 = f2bf(p1), h2 = f2bf(p2), h3 = f2bf(p3);
        unsigned short h4 = f2bf(p4), h5 = f2bf(p5), h6 = f2bf(p6), h7 = f2bf(p7);
        bf8 ah = {(short)h0, (short)h1, (short)h2, (short)h3,
                  (short)h4, (short)h5, (short)h6, (short)h7};
        bf8 al = {(short)f2bf(p0 - bf2f(h0)), (short)f2bf(p1 - bf2f(h1)),
                  (short)f2bf(p2 - bf2f(h2)), (short)f2bf(p3 - bf2f(h3)),
                  (short)f2bf(p4 - bf2f(h4)), (short)f2bf(p5 - bf2f(h5)),
                  (short)f2bf(p6 - bf2f(h6)), (short)f2bf(p7 - bf2f(h7))};
#pragma unroll
        for (int fj = 0; fj < 4; ++fj) {
            acc[fj] = MFMA(ah, vh_[fj], acc[fj]);
            acc[fj] = MFMA(al, vh_[fj], acc[fj]);
            acc[fj] = MFMA(ah, vl_[fj], acc[fj]);
        }
        c0 = n0; c1 = n1;
    }
    const int b = bh >> 4, h = bh & 15;
#pragma unroll
    for (int fj = 0; fj < 4; ++fj)
#pragma unroll
        for (int rg = 0; rg < 4; ++rg) {
            int ii = i0 + wid * 16 + g * 4 + rg;
            int d = fj * 16 + li;
            float val = acc[fj][rg];
            size_t o = ((size_t)b * 1024 + ii) * 1024 + h * 64 + d;
            unsigned short hv = f2bf(val);
            unsigned short lv = f2bf(val - bf2f(hv));
            ctx_hi[o] = hv; ctx_lo[o] = lv;
        }
}

extern "C" void kernel_launch(void* const* d_in, const int* in_sizes, int n_in,
                              void* d_out, int out_size, void* d_ws, size_t ws_size,
                              hipStream_t stream)
{
    const float* query = (const float*)d_in[0];
    const float* key_  = (const float*)d_in[1];
    const float* value = (const float*)d_in[2];
    const int*   mask  = (const int*)d_in[3];
    const float* Wq = (const float*)d_in[4];
    const float* bq = (const float*)d_in[5];
    const float* Wk = (const float*)d_in[6];
    const float* bk = (const float*)d_in[7];
    const float* Wv = (const float*)d_in[8];
    const float* bv = (const float*)d_in[9];
    const float* Wo = (const float*)d_in[10];
    const float* bo = (const float*)d_in[11];
    const float* emb = (const float*)d_in[12];

    // workspace (exactly 84,148,224 B = round-1 proven footprint)
    unsigned short* wt_hi = (unsigned short*)d_ws;           // [4][1024][1024]
    unsigned short* wt_lo = wt_hi + (size_t)4 * 1048576;
    unsigned short* qh_hi = wt_lo + (size_t)4 * 1048576;     // [64][1024][64]
    unsigned short* qh_lo = qh_hi + 4194304;
    unsigned short* kh_hi = qh_lo + 4194304;
    unsigned short* kh_lo = kh_hi + 4194304;
    unsigned short* vt_hi = kh_lo + 4194304;                 // [64][64][1024]
    unsigned short* vt_lo = vt_hi + 4194304;
    unsigned short* prel  = vt_lo + 4194304;                 // [65536][130] bf16
    // stats + bitmask overlay the (dead-after-projection) Wq^T-hi region:
    float* rowm   = (float*)d_ws;                            // [65536]
    float* rowsum = rowm + 65536;
    unsigned long long* mb = (unsigned long long*)(rowsum + 65536);  // [65536]
    // ctx reuses q-heads (dead after scores/relproj):
    unsigned short* ctx_hi = qh_hi;
    unsigned short* ctx_lo = qh_lo;
    // v-heads scratch lives in the out region (written last):
    unsigned short* vh_hi = (unsigned short*)d_out;          // 16 MB region
    unsigned short* vh_lo = vh_hi + 4194304;

    float* out  = (float*)d_out;
    float* attn = (float*)d_out + 4194304;

    dim3 blk(256);
    wtrans_kernel<<<dim3(16, 16, 4), blk, 0, stream>>>(Wq, Wk, Wv, Wo, wt_hi, wt_lo);
    proj_qkv_kernel<<<dim3(32, 8, 3), blk, 0, stream>>>(query, key_, value, wt_hi, wt_lo,
                                                        bq, bk, bv, qh_hi, qh_lo,
                                                        kh_hi, kh_lo, vh_hi, vh_lo);
    maskbits_kernel<<<dim3(256), blk, 0, stream>>>(mask, mb);   // after proj (mb overlays Wq^T)
    vtrans_kernel<<<dim3(16, 64, 2), blk, 0, stream>>>(vh_hi, vh_lo, vt_hi, vt_lo);
    relproj_kernel<<<dim3(512), blk, 0, stream>>>(qh_hi, emb, prel);
    scores_kernel<<<dim3(8, 64), blk, 0, stream>>>(qh_hi, qh_lo, kh_hi, kh_lo, prel, mb,
                                                   attn, rowm, rowsum);
    pv_kernel<<<dim3(16, 64), blk, 0, stream>>>(attn, vt_hi, vt_lo, rowm, rowsum, ctx_hi, ctx_lo);
    outproj_kernel<<<dim3(32, 8), blk, 0, stream>>>(ctx_hi, ctx_lo,
                                                    wt_hi + (size_t)3 * 1048576,
                                                    wt_lo + (size_t)3 * 1048576, bo, out);
}

// Round 7
// 538.533 us; speedup vs baseline: 1.0506x; 1.0506x over previous
//
#include <hip/hip_runtime.h>
#include <math.h>

#define BB 4
#define SS 1024
#define EE 1024
#define HH 16
#define DD 64
#define RR 129
#define PRELW 130   // Pr LDS row stride (ushorts)

typedef __attribute__((ext_vector_type(4))) float f32x4;
typedef __attribute__((ext_vector_type(4))) int   i32x4;
typedef __attribute__((ext_vector_type(8))) short bf8;   // 8 bf16 = 4 VGPR (MFMA A/B frag)
typedef __attribute__((ext_vector_type(4))) short s4v;   // 4 bf16 = 8B

#define MFMA(a, b, c) __builtin_amdgcn_mfma_f32_16x16x32_bf16(a, b, c, 0, 0, 0)

__device__ __forceinline__ float bf2f(unsigned short u) {
    return __uint_as_float(((unsigned)u) << 16);
}
__device__ __forceinline__ unsigned short f2bf(float x) {  // RNE
    unsigned u = __float_as_uint(x);
    return (unsigned short)((u + 0x7fffu + ((u >> 16) & 1u)) >> 16);
}

// ---------------------------------------------------------------------------
// Weight transpose+split: W[K][N] fp32 -> Wt_hi/lo[N][K] bf16.
// ---------------------------------------------------------------------------
__global__ __launch_bounds__(256, 4)
void wtrans_kernel(const float* __restrict__ Wq, const float* __restrict__ Wk,
                   const float* __restrict__ Wv, const float* __restrict__ Wo,
                   unsigned short* __restrict__ wt_hi, unsigned short* __restrict__ wt_lo)
{
    __shared__ float T[64][65];
    const int w = blockIdx.z;
    const float* W = w == 0 ? Wq : (w == 1 ? Wk : (w == 2 ? Wv : Wo));
    const int n0 = blockIdx.x * 64, k0 = blockIdx.y * 64;
    const int tid = threadIdx.x;
#pragma unroll
    for (int i = 0; i < 4; ++i) {
        int c = tid + 256 * i; int r = c >> 4, c4 = c & 15;
        f32x4 v = *(const f32x4*)(W + (size_t)(k0 + r) * EE + n0 + c4 * 4);
        T[r][c4 * 4 + 0] = v.x; T[r][c4 * 4 + 1] = v.y;
        T[r][c4 * 4 + 2] = v.z; T[r][c4 * 4 + 3] = v.w;
    }
    __syncthreads();
#pragma unroll
    for (int i = 0; i < 4; ++i) {
        int c = tid + 256 * i; int r = c >> 4, c4 = c & 15;   // r = n_local, c4 = k group
        float x0 = T[c4 * 4 + 0][r], x1 = T[c4 * 4 + 1][r];
        float x2 = T[c4 * 4 + 2][r], x3 = T[c4 * 4 + 3][r];
        unsigned short h0 = f2bf(x0), h1 = f2bf(x1), h2 = f2bf(x2), h3 = f2bf(x3);
        unsigned short l0 = f2bf(x0 - bf2f(h0)), l1 = f2bf(x1 - bf2f(h1));
        unsigned short l2 = f2bf(x2 - bf2f(h2)), l3 = f2bf(x3 - bf2f(h3));
        size_t o = (size_t)w * 1048576 + (size_t)(n0 + r) * 1024 + k0 + c4 * 4;
        *(s4v*)&wt_hi[o] = (s4v){(short)h0, (short)h1, (short)h2, (short)h3};
        *(s4v*)&wt_lo[o] = (s4v){(short)l0, (short)l1, (short)l2, (short)l3};
    }
}

// ---------------------------------------------------------------------------
// Pack attn_mask int32 -> bitmask u64 words. One thread per word (64 ints).
// ---------------------------------------------------------------------------
__global__ __launch_bounds__(256)
void maskbits_kernel(const int* __restrict__ mask, unsigned long long* __restrict__ mb)
{
    const int w = blockIdx.x * 256 + threadIdx.x;   // 65536 words
    const int* p = mask + (size_t)w * 64;
    unsigned long long bits = 0;
#pragma unroll
    for (int i = 0; i < 16; ++i) {
        int4 v = *(const int4*)(p + i * 4);
        bits |= (unsigned long long)(v.x != 0) << (i * 4 + 0);
        bits |= (unsigned long long)(v.y != 0) << (i * 4 + 1);
        bits |= (unsigned long long)(v.z != 0) << (i * 4 + 2);
        bits |= (unsigned long long)(v.w != 0) << (i * 4 + 3);
    }
    mb[w] = bits;
}

// ---------------------------------------------------------------------------
// Split-bf16 MFMA GEMM body (projections / out-proj).
// ---------------------------------------------------------------------------
template<int ASRC, int EPI>
__device__ __forceinline__ void gemm_body(
    const float* __restrict__ Af,
    const unsigned short* __restrict__ Ah_g, const unsigned short* __restrict__ Al_g,
    const unsigned short* __restrict__ Bh_g, const unsigned short* __restrict__ Bl_g,
    const float* __restrict__ bias,
    float* __restrict__ Yf, unsigned short* __restrict__ Yh, unsigned short* __restrict__ Yl,
    unsigned short* As_h, unsigned short* As_l, unsigned short* Bs_h, unsigned short* Bs_l,
    int m0, int n0)
{
    const int tid = threadIdx.x, lane = tid & 63, wid = tid >> 6;
    const int wm = (wid >> 1) * 64, wn = (wid & 1) * 64;
    f32x4 zero4 = {0.f, 0.f, 0.f, 0.f};
    f32x4 acc[4][4];
#pragma unroll
    for (int a = 0; a < 4; ++a)
#pragma unroll
        for (int b = 0; b < 4; ++b) acc[a][b] = zero4;

    for (int kt = 0; kt < 1024; kt += 64) {
        __syncthreads();
        if (ASRC == 0) {
#pragma unroll
            for (int i = 0; i < 8; ++i) {
                int c = tid + 256 * i; int r = c >> 4, c4 = c & 15;
                f32x4 v = *(const f32x4*)(Af + (size_t)(m0 + r) * 1024 + kt + c4 * 4);
                unsigned short h0 = f2bf(v.x), h1 = f2bf(v.y), h2 = f2bf(v.z), h3 = f2bf(v.w);
                unsigned short l0 = f2bf(v.x - bf2f(h0)), l1 = f2bf(v.y - bf2f(h1));
                unsigned short l2 = f2bf(v.z - bf2f(h2)), l3 = f2bf(v.w - bf2f(h3));
                int off = r * 64 + (((c4 >> 1) ^ (r & 7)) * 8) + (c4 & 1) * 4;
                *(s4v*)&As_h[off] = (s4v){(short)h0, (short)h1, (short)h2, (short)h3};
                *(s4v*)&As_l[off] = (s4v){(short)l0, (short)l1, (short)l2, (short)l3};
            }
        } else {
#pragma unroll
            for (int i = 0; i < 4; ++i) {
                int c = tid + 256 * i; int r = c >> 3, cc = c & 7;
                int off = r * 64 + ((cc ^ (r & 7)) * 8);
                *(bf8*)&As_h[off] = *(const bf8*)(Ah_g + (size_t)(m0 + r) * 1024 + kt + cc * 8);
                *(bf8*)&As_l[off] = *(const bf8*)(Al_g + (size_t)(m0 + r) * 1024 + kt + cc * 8);
            }
        }
#pragma unroll
        for (int i = 0; i < 4; ++i) {
            int c = tid + 256 * i; int r = c >> 3, cc = c & 7;
            int off = r * 64 + ((cc ^ (r & 7)) * 8);
            *(bf8*)&Bs_h[off] = *(const bf8*)(Bh_g + (size_t)(n0 + r) * 1024 + kt + cc * 8);
            *(bf8*)&Bs_l[off] = *(const bf8*)(Bl_g + (size_t)(n0 + r) * 1024 + kt + cc * 8);
        }
        __syncthreads();
#pragma unroll
        for (int ks = 0; ks < 2; ++ks) {
            bf8 ah[4], al[4], bh[4], bl[4];
#pragma unroll
            for (int f = 0; f < 4; ++f) {
                int ra = wm + f * 16 + (lane & 15);
                int ca = (ks * 4 + (lane >> 4)) ^ (ra & 7);
                ah[f] = *(const bf8*)&As_h[ra * 64 + ca * 8];
                al[f] = *(const bf8*)&As_l[ra * 64 + ca * 8];
                int rb = wn + f * 16 + (lane & 15);
                int cb = (ks * 4 + (lane >> 4)) ^ (rb & 7);
                bh[f] = *(const bf8*)&Bs_h[rb * 64 + cb * 8];
                bl[f] = *(const bf8*)&Bs_l[rb * 64 + cb * 8];
            }
#pragma unroll
            for (int fi = 0; fi < 4; ++fi)
#pragma unroll
                for (int fj = 0; fj < 4; ++fj) {
                    acc[fi][fj] = MFMA(ah[fi], bh[fj], acc[fi][fj]);
                    acc[fi][fj] = MFMA(al[fi], bh[fj], acc[fi][fj]);
                    acc[fi][fj] = MFMA(ah[fi], bl[fj], acc[fi][fj]);
                }
        }
    }
    // epilogue: C/D layout (m89): col = lane&15, row = (lane>>4)*4 + reg
#pragma unroll
    for (int fi = 0; fi < 4; ++fi)
#pragma unroll
        for (int fj = 0; fj < 4; ++fj)
#pragma unroll
            for (int rg = 0; rg < 4; ++rg) {
                int m = m0 + wm + fi * 16 + ((lane >> 4) << 2) + rg;
                int n = n0 + wn + fj * 16 + (lane & 15);
                float val = acc[fi][fj][rg] + bias[n];
                if (EPI == 0) {
                    int b = m >> 10, s = m & 1023, h = n >> 6, d = n & 63;
                    size_t o = (((size_t)(b * 16 + h)) * 1024 + s) * 64 + d;
                    unsigned short hv = f2bf(val);
                    unsigned short lv = f2bf(val - bf2f(hv));
                    Yh[o] = hv; Yl[o] = lv;
                } else {
                    Yf[(size_t)m * 1024 + n] = val;
                }
            }
}

__global__ __launch_bounds__(256, 2)
void proj_qkv_kernel(const float* __restrict__ q_in, const float* __restrict__ k_in,
                     const float* __restrict__ v_in,
                     const unsigned short* __restrict__ wt_hi, const unsigned short* __restrict__ wt_lo,
                     const float* __restrict__ bq, const float* __restrict__ bk,
                     const float* __restrict__ bv,
                     unsigned short* qh_hi, unsigned short* qh_lo,
                     unsigned short* kh_hi, unsigned short* kh_lo,
                     unsigned short* vh_hi, unsigned short* vh_lo)
{
    __shared__ __align__(16) unsigned short As_h[128 * 64], As_l[128 * 64];
    __shared__ __align__(16) unsigned short Bs_h[128 * 64], Bs_l[128 * 64];
    const int z = blockIdx.z;
    const float* X = z == 0 ? q_in : (z == 1 ? k_in : v_in);
    const float* bias = z == 0 ? bq : (z == 1 ? bk : bv);
    unsigned short* Yh = z == 0 ? qh_hi : (z == 1 ? kh_hi : vh_hi);
    unsigned short* Yl = z == 0 ? qh_lo : (z == 1 ? kh_lo : vh_lo);
    gemm_body<0, 0>(X, nullptr, nullptr,
                    wt_hi + (size_t)z * 1048576, wt_lo + (size_t)z * 1048576,
                    bias, nullptr, Yh, Yl, As_h, As_l, Bs_h, Bs_l,
                    blockIdx.x * 128, blockIdx.y * 128);
}

__global__ __launch_bounds__(256, 2)
void outproj_kernel(const unsigned short* __restrict__ ctx_hi, const unsigned short* __restrict__ ctx_lo,
                    const unsigned short* __restrict__ wo_hi, const unsigned short* __restrict__ wo_lo,
                    const float* __restrict__ bo, float* __restrict__ out)
{
    __shared__ __align__(16) unsigned short As_h[128 * 64], As_l[128 * 64];
    __shared__ __align__(16) unsigned short Bs_h[128 * 64], Bs_l[128 * 64];
    gemm_body<1, 1>(nullptr, ctx_hi, ctx_lo, wo_hi, wo_lo, bo, out, nullptr, nullptr,
                    As_h, As_l, Bs_h, Bs_l, blockIdx.x * 128, blockIdx.y * 128);
}

// ---------------------------------------------------------------------------
// V transpose: vh[bh][s][d] (ushort) -> vt[bh][d][s]. z: 0=hi,1=lo buffers.
// ---------------------------------------------------------------------------
__global__ __launch_bounds__(256, 4)
void vtrans_kernel(const unsigned short* __restrict__ vh_hi, const unsigned short* __restrict__ vh_lo,
                   unsigned short* __restrict__ vt_hi, unsigned short* __restrict__ vt_lo)
{
    __shared__ unsigned short T[64][72];
    const unsigned short* src = blockIdx.z ? vh_lo : vh_hi;
    unsigned short* dst = blockIdx.z ? vt_lo : vt_hi;
    const int st = blockIdx.x * 64, bh = blockIdx.y, tid = threadIdx.x;
#pragma unroll
    for (int i = 0; i < 4; ++i) {
        int c = tid + 256 * i; int r = c >> 4, d4 = c & 15;
        s4v v = *(const s4v*)(src + ((size_t)bh * 1024 + st + r) * 64 + d4 * 4);
        T[r][d4 * 4 + 0] = (unsigned short)v.x; T[r][d4 * 4 + 1] = (unsigned short)v.y;
        T[r][d4 * 4 + 2] = (unsigned short)v.z; T[r][d4 * 4 + 3] = (unsigned short)v.w;
    }
    __syncthreads();
#pragma unroll
    for (int i = 0; i < 4; ++i) {
        int c = tid + 256 * i; int r = c >> 4, s4_ = c & 15;  // r = d row
        s4v o = {(short)T[s4_ * 4 + 0][r], (short)T[s4_ * 4 + 1][r],
                 (short)T[s4_ * 4 + 2][r], (short)T[s4_ * 4 + 3][r]};
        *(s4v*)(dst + ((size_t)bh * 64 + r) * 1024 + st + s4_ * 4) = o;
    }
}

// ---------------------------------------------------------------------------
// Fused attention: per block 128 i-rows x one head.
//   prologue: stage Q (swizzled), compute rel-bias Pr in LDS via MFMA(q, emb)
//   pass 1:   jt loop, swapped QK^T MFMA, online max/sum stats (no stores)
//   pass 2:   recompute QK^T, p = exp(s-m)*inv, write final weights (f32x4),
//             shfl-redistribute P to A-frag layout, PV MFMA vs vt from global
//   reduce:   ctx_acc summed across the wj wave pair via LDS (Sh/Sl reused)
// ---------------------------------------------------------------------------
__global__ __launch_bounds__(256, 2)
void attn_fused_kernel(const unsigned short* __restrict__ qh_hi, const unsigned short* __restrict__ qh_lo,
                       const unsigned short* __restrict__ kh_hi, const unsigned short* __restrict__ kh_lo,
                       const unsigned short* __restrict__ vt_hi, const unsigned short* __restrict__ vt_lo,
                       const float* __restrict__ emb, const unsigned long long* __restrict__ mb,
                       float* __restrict__ attn,
                       unsigned short* __restrict__ ctx_hi, unsigned short* __restrict__ ctx_lo)
{
    __shared__ __align__(16) unsigned short Sh[128 * 64], Sl[128 * 64];  // Q then K tiles
    __shared__ __align__(16) unsigned short Pr[128 * PRELW];
    __shared__ float Sm[2][128], Ss[2][128], SmF[128], SsF[128];
    const int tid = threadIdx.x, lane = tid & 63, wid = tid >> 6;
    const int wi = wid >> 1, wj = wid & 1;
    const int g = lane >> 4, li = lane & 15;
    const int i0 = blockIdx.x * 128, bh = blockIdx.y, b = bh >> 4;
    const f32x4 zero4 = {0.f, 0.f, 0.f, 0.f};

    // ---- stage Q tile (swizzled rows = i) ----
    const unsigned short* qbh = qh_hi + ((size_t)bh * 1024 + i0) * 64;
    const unsigned short* qbl = qh_lo + ((size_t)bh * 1024 + i0) * 64;
#pragma unroll
    for (int i = 0; i < 4; ++i) {
        int c = tid + 256 * i; int r = c >> 3, cc = c & 7;
        int off = r * 64 + ((cc ^ (r & 7)) * 8);
        *(bf8*)&Sh[off] = *(const bf8*)(qbh + r * 64 + cc * 8);
        *(bf8*)&Sl[off] = *(const bf8*)(qbl + r * 64 + cc * 8);
    }
    __syncthreads();

    // ---- Q fragments to registers ----
    bf8 qfh[4][2], qfl[4][2];
#pragma unroll
    for (int fi = 0; fi < 4; ++fi)
#pragma unroll
        for (int ks = 0; ks < 2; ++ks) {
            int rb = wi * 64 + fi * 16 + li;
            int cb = (ks * 4 + g) ^ (rb & 7);
            qfh[fi][ks] = *(const bf8*)&Sh[rb * 64 + cb * 8];
            qfl[fi][ks] = *(const bf8*)&Sl[rb * 64 + cb * 8];
        }

    // ---- rel-bias Pr[i][r] = q_hi[i]. emb[r] via MFMA, stored bf16 ----
    for (int t = wid; t < 72; t += 4) {       // 8 i-tiles x 9 r-tiles
        const int it = t / 9, rt = t % 9;
        f32x4 pc = zero4;
#pragma unroll
        for (int ks = 0; ks < 2; ++ks) {
            int ra = it * 16 + li;
            int ca = (ks * 4 + g) ^ (ra & 7);
            bf8 aq = *(const bf8*)&Sh[ra * 64 + ca * 8];
            int er = rt * 16 + li; if (er > 128) er = 128;   // clamp OOB rows
            const float* ep = emb + (size_t)er * 64 + ks * 32 + g * 8;
            f32x4 e0 = *(const f32x4*)ep;
            f32x4 e1 = *(const f32x4*)(ep + 4);
            bf8 be = {(short)f2bf(e0.x), (short)f2bf(e0.y), (short)f2bf(e0.z), (short)f2bf(e0.w),
                      (short)f2bf(e1.x), (short)f2bf(e1.y), (short)f2bf(e1.z), (short)f2bf(e1.w)};
            pc = MFMA(aq, be, pc);
        }
        const int rcol = rt * 16 + li;
        if (rcol < RR) {
#pragma unroll
            for (int rg = 0; rg < 4; ++rg)
                Pr[(it * 16 + g * 4 + rg) * PRELW + rcol] = f2bf(pc[rg]);
        }
    }

    float rm[4], rs[4];
#pragma unroll
    for (int i = 0; i < 4; ++i) { rm[i] = -3.0e38f; rs[i] = 0.f; }

    // ================= PASS 1: stats only =================
    for (int jt = 0; jt < 8; ++jt) {
        __syncthreads();   // Pr writes done (jt=0); prior frag reads done (jt>0)
        const unsigned short* kbh = kh_hi + ((size_t)bh * 1024 + jt * 128) * 64;
        const unsigned short* kbl = kh_lo + ((size_t)bh * 1024 + jt * 128) * 64;
#pragma unroll
        for (int i = 0; i < 4; ++i) {
            int c = tid + 256 * i; int r = c >> 3, cc = c & 7;
            int off = r * 64 + ((cc ^ (r & 7)) * 8);
            *(bf8*)&Sh[off] = *(const bf8*)(kbh + r * 64 + cc * 8);
            *(bf8*)&Sl[off] = *(const bf8*)(kbl + r * 64 + cc * 8);
        }
        __syncthreads();
        f32x4 acc[4][4];  // [fj][fi]
#pragma unroll
        for (int a = 0; a < 4; ++a)
#pragma unroll
            for (int c = 0; c < 4; ++c) acc[a][c] = zero4;
#pragma unroll
        for (int ks = 0; ks < 2; ++ks) {
            bf8 kfh[4], kfl[4];
#pragma unroll
            for (int fj = 0; fj < 4; ++fj) {
                int ra = wj * 64 + fj * 16 + li;
                int ca = (ks * 4 + g) ^ (ra & 7);
                kfh[fj] = *(const bf8*)&Sh[ra * 64 + ca * 8];
                kfl[fj] = *(const bf8*)&Sl[ra * 64 + ca * 8];
            }
#pragma unroll
            for (int fj = 0; fj < 4; ++fj)
#pragma unroll
                for (int fi = 0; fi < 4; ++fi) {
                    acc[fj][fi] = MFMA(kfh[fj], qfh[fi][ks], acc[fj][fi]);
                    acc[fj][fi] = MFMA(kfl[fj], qfh[fi][ks], acc[fj][fi]);
                    acc[fj][fi] = MFMA(kfh[fj], qfl[fi][ks], acc[fj][fi]);
                }
        }
#pragma unroll
        for (int fi = 0; fi < 4; ++fi) {
            const int rowL = wi * 64 + fi * 16 + li;
            const int ii = i0 + rowL;
            const unsigned long long mw = mb[((size_t)b * 1024 + ii) * 16 + jt * 2 + wj];
            float p16[4][4];
            float tmax = -3.0e38f;
#pragma unroll
            for (int fj = 0; fj < 4; ++fj)
#pragma unroll
                for (int rg = 0; rg < 4; ++rg) {
                    int jloc = fj * 16 + g * 4 + rg;
                    int jj = jt * 128 + wj * 64 + jloc;
                    int dd = ii - jj; dd = dd < -64 ? -64 : (dd > 64 ? 64 : dd);
                    float s = acc[fj][fi][rg] * 0.125f + bf2f(Pr[rowL * PRELW + dd + 64]);
                    if (!((mw >> jloc) & 1ull)) s = -1.0e30f;
                    p16[fj][rg] = s;
                    tmax = fmaxf(tmax, s);
                }
            tmax = fmaxf(tmax, __shfl_xor(tmax, 16, 64));
            tmax = fmaxf(tmax, __shfl_xor(tmax, 32, 64));
            float nm = fmaxf(rm[fi], tmax);
            float ps = 0.f;
#pragma unroll
            for (int fj = 0; fj < 4; ++fj)
#pragma unroll
                for (int rg = 0; rg < 4; ++rg) ps += __expf(p16[fj][rg] - nm);
            ps += __shfl_xor(ps, 16, 64);
            ps += __shfl_xor(ps, 32, 64);
            rs[fi] = rs[fi] * __expf(rm[fi] - nm) + ps;
            rm[fi] = nm;
        }
    }
    // combine the two j-half waves per i-row
#pragma unroll
    for (int fi = 0; fi < 4; ++fi) {
        if (lane < 16) {
            Sm[wj][wi * 64 + fi * 16 + li] = rm[fi];
            Ss[wj][wi * 64 + fi * 16 + li] = rs[fi];
        }
    }
    __syncthreads();
    if (tid < 128) {
        float m0_ = Sm[0][tid], m1_ = Sm[1][tid];
        float mmx = fmaxf(m0_, m1_);
        SmF[tid] = mmx;
        SsF[tid] = Ss[0][tid] * __expf(m0_ - mmx) + Ss[1][tid] * __expf(m1_ - mmx);
    }
    __syncthreads();
    float mm4[4], iv4[4];
#pragma unroll
    for (int fi = 0; fi < 4; ++fi) {
        mm4[fi] = SmF[wi * 64 + fi * 16 + li];
        iv4[fi] = 1.f / SsF[wi * 64 + fi * 16 + li];
    }

    f32x4 ctx_acc[4][4];  // [fi][fd]
#pragma unroll
    for (int a = 0; a < 4; ++a)
#pragma unroll
        for (int c = 0; c < 4; ++c) ctx_acc[a][c] = zero4;

    // ================= PASS 2: weights write + PV =================
    for (int jt = 0; jt < 8; ++jt) {
        __syncthreads();
        const unsigned short* kbh = kh_hi + ((size_t)bh * 1024 + jt * 128) * 64;
        const unsigned short* kbl = kh_lo + ((size_t)bh * 1024 + jt * 128) * 64;
#pragma unroll
        for (int i = 0; i < 4; ++i) {
            int c = tid + 256 * i; int r = c >> 3, cc = c & 7;
            int off = r * 64 + ((cc ^ (r & 7)) * 8);
            *(bf8*)&Sh[off] = *(const bf8*)(kbh + r * 64 + cc * 8);
            *(bf8*)&Sl[off] = *(const bf8*)(kbl + r * 64 + cc * 8);
        }
        __syncthreads();
        f32x4 acc[4][4];  // identical recompute -> identical s values
#pragma unroll
        for (int a = 0; a < 4; ++a)
#pragma unroll
            for (int c = 0; c < 4; ++c) acc[a][c] = zero4;
#pragma unroll
        for (int ks = 0; ks < 2; ++ks) {
            bf8 kfh[4], kfl[4];
#pragma unroll
            for (int fj = 0; fj < 4; ++fj) {
                int ra = wj * 64 + fj * 16 + li;
                int ca = (ks * 4 + g) ^ (ra & 7);
                kfh[fj] = *(const bf8*)&Sh[ra * 64 + ca * 8];
                kfl[fj] = *(const bf8*)&Sl[ra * 64 + ca * 8];
            }
#pragma unroll
            for (int fj = 0; fj < 4; ++fj)
#pragma unroll
                for (int fi = 0; fi < 4; ++fi) {
                    acc[fj][fi] = MFMA(kfh[fj], qfh[fi][ks], acc[fj][fi]);
                    acc[fj][fi] = MFMA(kfl[fj], qfh[fi][ks], acc[fj][fi]);
                    acc[fj][fi] = MFMA(kfh[fj], qfl[fi][ks], acc[fj][fi]);
                }
        }
        // per 32-j chunk: V frags from global vt, p+store+pack, shfl, PV MFMA
#pragma unroll
        for (int c = 0; c < 2; ++c) {
            bf8 vfh[4], vfl[4];
#pragma unroll
            for (int fd = 0; fd < 4; ++fd) {
                size_t vb = (size_t)bh * 65536 + (size_t)(fd * 16 + li) * 1024
                          + jt * 128 + wj * 64 + c * 32 + g * 8;
                vfh[fd] = *(const bf8*)(vt_hi + vb);
                vfl[fd] = *(const bf8*)(vt_lo + vb);
            }
#pragma unroll
            for (int fi = 0; fi < 4; ++fi) {
                const int rowL = wi * 64 + fi * 16 + li;
                const int ii = i0 + rowL;
                const unsigned long long mw = mb[((size_t)b * 1024 + ii) * 16 + jt * 2 + wj];
                const float mmf = mm4[fi], ivf = iv4[fi];
                float* arow = attn + ((size_t)bh * 1024 + ii) * 1024 + jt * 128 + wj * 64 + g * 4;
                unsigned wh[2][2], wl[2][2];
#pragma unroll
                for (int t = 0; t < 2; ++t) {
                    const int fj = c * 2 + t;
                    f32x4 pv;
#pragma unroll
                    for (int rg = 0; rg < 4; ++rg) {
                        int jloc = fj * 16 + g * 4 + rg;
                        int jj = jt * 128 + wj * 64 + jloc;
                        int dd = ii - jj; dd = dd < -64 ? -64 : (dd > 64 ? 64 : dd);
                        float s = acc[fj][fi][rg] * 0.125f + bf2f(Pr[rowL * PRELW + dd + 64]);
                        if (!((mw >> jloc) & 1ull)) s = -1.0e30f;
                        pv[rg] = __expf(s - mmf) * ivf;
                    }
                    *(f32x4*)(arow + fj * 16) = pv;   // final attention weights
                    unsigned short h0 = f2bf(pv.x), h1 = f2bf(pv.y), h2 = f2bf(pv.z), h3 = f2bf(pv.w);
                    wh[t][0] = (unsigned)h0 | ((unsigned)h1 << 16);
                    wh[t][1] = (unsigned)h2 | ((unsigned)h3 << 16);
                    unsigned short l0 = f2bf(pv.x - bf2f(h0)), l1 = f2bf(pv.y - bf2f(h1));
                    unsigned short l2 = f2bf(pv.z - bf2f(h2)), l3 = f2bf(pv.w - bf2f(h3));
                    wl[t][0] = (unsigned)l0 | ((unsigned)l1 << 16);
                    wl[t][1] = (unsigned)l2 | ((unsigned)l3 << 16);
                }
                // redistribute: dest lane g needs tile (g>>1), source groups (g&1)*2, +1
                const int src0 = ((g & 1) * 2) * 16 + li;
                const int src1 = src0 + 16;
                const bool hiT = (g >> 1) & 1;
                int x0A = __shfl((int)wh[0][0], src0, 64), x0B = __shfl((int)wh[1][0], src0, 64);
                int x1A = __shfl((int)wh[0][1], src0, 64), x1B = __shfl((int)wh[1][1], src0, 64);
                int x2A = __shfl((int)wh[0][0], src1, 64), x2B = __shfl((int)wh[1][0], src1, 64);
                int x3A = __shfl((int)wh[0][1], src1, 64), x3B = __shfl((int)wh[1][1], src1, 64);
                i32x4 awh = {hiT ? x0B : x0A, hiT ? x1B : x1A, hiT ? x2B : x2A, hiT ? x3B : x3A};
                bf8 pah = *(bf8*)&awh;
                int y0A = __shfl((int)wl[0][0], src0, 64), y0B = __shfl((int)wl[1][0], src0, 64);
                int y1A = __shfl((int)wl[0][1], src0, 64), y1B = __shfl((int)wl[1][1], src0, 64);
                int y2A = __shfl((int)wl[0][0], src1, 64), y2B = __shfl((int)wl[1][0], src1, 64);
                int y3A = __shfl((int)wl[0][1], src1, 64), y3B = __shfl((int)wl[1][1], src1, 64);
                i32x4 awl = {hiT ? y0B : y0A, hiT ? y1B : y1A, hiT ? y2B : y2A, hiT ? y3B : y3A};
                bf8 pal = *(bf8*)&awl;
#pragma unroll
                for (int fd = 0; fd < 4; ++fd) {
                    ctx_acc[fi][fd] = MFMA(pah, vfh[fd], ctx_acc[fi][fd]);
                    ctx_acc[fi][fd] = MFMA(pal, vfh[fd], ctx_acc[fi][fd]);
                    ctx_acc[fi][fd] = MFMA(pah, vfl[fd], ctx_acc[fi][fd]);
                }
            }
        }
    }

    // ---- reduce ctx_acc across the wj wave pair (Sh/Sl reused as scratch) ----
    __syncthreads();                         // all waves done reading Sh/Sl
    float* red = (wi == 0) ? (float*)Sh : (float*)Sl;   // 4096 floats each
    if (wj == 1) {
#pragma unroll
        for (int fi = 0; fi < 4; ++fi)
#pragma unroll
            for (int fd = 0; fd < 4; ++fd)
#pragma unroll
                for (int rg = 0; rg < 4; ++rg) {
                    int idx = (fi * 4 + fd) * 4 + rg;
                    red[lane * 64 + ((idx + lane) & 63)] = ctx_acc[fi][fd][rg];
                }
    }
    __syncthreads();
    if (wj == 0) {
        const int b_ = bh >> 4, h = bh & 15;
#pragma unroll
        for (int fi = 0; fi < 4; ++fi)
#pragma unroll
            for (int fd = 0; fd < 4; ++fd)
#pragma unroll
                for (int rg = 0; rg < 4; ++rg) {
                    int idx = (fi * 4 + fd) * 4 + rg;
                    float val = ctx_acc[fi][fd][rg] + red[lane * 64 + ((idx + lane) & 63)];
                    int ii = i0 + wi * 64 + fi * 16 + g * 4 + rg;
                    int d = fd * 16 + li;
                    size_t o = ((size_t)b_ * 1024 + ii) * 1024 + h * 64 + d;
                    unsigned short hv = f2bf(val);
                    unsigned short lv = f2bf(val - bf2f(hv));
                    ctx_hi[o] = hv; ctx_lo[o] = lv;
                }
    }
}

extern "C" void kernel_launch(void* const* d_in, const int* in_sizes, int n_in,
                              void* d_out, int out_size, void* d_ws, size_t ws_size,
                              hipStream_t stream)
{
    const float* query = (const float*)d_in[0];
    const float* key_  = (const float*)d_in[1];
    const float* value = (const float*)d_in[2];
    const int*   mask  = (const int*)d_in[3];
    const float* Wq = (const float*)d_in[4];
    const float* bq = (const float*)d_in[5];
    const float* Wk = (const float*)d_in[6];
    const float* bk = (const float*)d_in[7];
    const float* Wv = (const float*)d_in[8];
    const float* bv = (const float*)d_in[9];
    const float* Wo = (const float*)d_in[10];
    const float* bo = (const float*)d_in[11];
    const float* emb = (const float*)d_in[12];

    // workspace: 80.0 MB (<= 84.1 MB proven in earlier rounds)
    unsigned short* wt_hi = (unsigned short*)d_ws;           // [4][1024][1024]
    unsigned short* wt_lo = wt_hi + (size_t)4 * 1048576;
    unsigned short* qh_hi = wt_lo + (size_t)4 * 1048576;     // [64][1024][64]
    unsigned short* qh_lo = qh_hi + 4194304;
    unsigned short* kh_hi = qh_lo + 4194304;
    unsigned short* kh_lo = kh_hi + 4194304;
    unsigned short* vt_hi = kh_lo + 4194304;                 // [64][64][1024]
    unsigned short* vt_lo = vt_hi + 4194304;
    unsigned short* ctx_hi = vt_lo + 4194304;                // [4][1024][1024]
    unsigned short* ctx_lo = ctx_hi + 4194304;
    // bitmask overlays the (dead-after-projection) Wq^T-hi region:
    unsigned long long* mb = (unsigned long long*)d_ws;      // [65536] = 512 KB
    // v-heads scratch lives in the out region (dead after vtrans; out written last):
    unsigned short* vh_hi = (unsigned short*)d_out;          // 16 MB region
    unsigned short* vh_lo = vh_hi + 4194304;

    float* out  = (float*)d_out;
    float* attn = (float*)d_out + 4194304;

    dim3 blk(256);
    wtrans_kernel<<<dim3(16, 16, 4), blk, 0, stream>>>(Wq, Wk, Wv, Wo, wt_hi, wt_lo);
    proj_qkv_kernel<<<dim3(32, 8, 3), blk, 0, stream>>>(query, key_, value, wt_hi, wt_lo,
                                                        bq, bk, bv, qh_hi, qh_lo,
                                                        kh_hi, kh_lo, vh_hi, vh_lo);
    maskbits_kernel<<<dim3(256), blk, 0, stream>>>(mask, mb);   // after proj (mb overlays Wq^T)
    vtrans_kernel<<<dim3(16, 64, 2), blk, 0, stream>>>(vh_hi, vh_lo, vt_hi, vt_lo);
    attn_fused_kernel<<<dim3(8, 64), blk, 0, stream>>>(qh_hi, qh_lo, kh_hi, kh_lo,
                                                       vt_hi, vt_lo, emb, mb,
                                                       attn, ctx_hi, ctx_lo);
    outproj_kernel<<<dim3(32, 8), blk, 0, stream>>>(ctx_hi, ctx_lo,
                                                    wt_hi + (size_t)3 * 1048576,
                                                    wt_lo + (size_t)3 * 1048576, bo, out);
}

// Round 8
// 481.922 us; speedup vs baseline: 1.1740x; 1.1175x over previous
//
#include <hip/hip_runtime.h>
#include <math.h>

#define BB 4
#define SS 1024
#define EE 1024
#define HH 16
#define DD 64
#define RR 129
#define PRELW 130   // Pr LDS row stride (ushorts)

typedef __attribute__((ext_vector_type(4))) float f32x4;
typedef __attribute__((ext_vector_type(4))) int   i32x4;
typedef __attribute__((ext_vector_type(8))) short bf8;   // 8 bf16 = 4 VGPR (MFMA A/B frag)
typedef __attribute__((ext_vector_type(4))) short s4v;   // 4 bf16 = 8B

#define MFMA(a, b, c) __builtin_amdgcn_mfma_f32_16x16x32_bf16(a, b, c, 0, 0, 0)

__device__ __forceinline__ float bf2f(unsigned short u) {
    return __uint_as_float(((unsigned)u) << 16);
}
__device__ __forceinline__ unsigned short f2bf(float x) {  // RNE
    unsigned u = __float_as_uint(x);
    return (unsigned short)((u + 0x7fffu + ((u >> 16) & 1u)) >> 16);
}

// ---------------------------------------------------------------------------
// Weight transpose+split: W[K][N] fp32 -> Wt_hi/lo[N][K] bf16.
// ---------------------------------------------------------------------------
__global__ __launch_bounds__(256, 4)
void wtrans_kernel(const float* __restrict__ Wq, const float* __restrict__ Wk,
                   const float* __restrict__ Wv, const float* __restrict__ Wo,
                   unsigned short* __restrict__ wt_hi, unsigned short* __restrict__ wt_lo)
{
    __shared__ float T[64][65];
    const int w = blockIdx.z;
    const float* W = w == 0 ? Wq : (w == 1 ? Wk : (w == 2 ? Wv : Wo));
    const int n0 = blockIdx.x * 64, k0 = blockIdx.y * 64;
    const int tid = threadIdx.x;
#pragma unroll
    for (int i = 0; i < 4; ++i) {
        int c = tid + 256 * i; int r = c >> 4, c4 = c & 15;
        f32x4 v = *(const f32x4*)(W + (size_t)(k0 + r) * EE + n0 + c4 * 4);
        T[r][c4 * 4 + 0] = v.x; T[r][c4 * 4 + 1] = v.y;
        T[r][c4 * 4 + 2] = v.z; T[r][c4 * 4 + 3] = v.w;
    }
    __syncthreads();
#pragma unroll
    for (int i = 0; i < 4; ++i) {
        int c = tid + 256 * i; int r = c >> 4, c4 = c & 15;   // r = n_local, c4 = k group
        float x0 = T[c4 * 4 + 0][r], x1 = T[c4 * 4 + 1][r];
        float x2 = T[c4 * 4 + 2][r], x3 = T[c4 * 4 + 3][r];
        unsigned short h0 = f2bf(x0), h1 = f2bf(x1), h2 = f2bf(x2), h3 = f2bf(x3);
        unsigned short l0 = f2bf(x0 - bf2f(h0)), l1 = f2bf(x1 - bf2f(h1));
        unsigned short l2 = f2bf(x2 - bf2f(h2)), l3 = f2bf(x3 - bf2f(h3));
        size_t o = (size_t)w * 1048576 + (size_t)(n0 + r) * 1024 + k0 + c4 * 4;
        *(s4v*)&wt_hi[o] = (s4v){(short)h0, (short)h1, (short)h2, (short)h3};
        *(s4v*)&wt_lo[o] = (s4v){(short)l0, (short)l1, (short)l2, (short)l3};
    }
}

// ---------------------------------------------------------------------------
// Pack attn_mask int32 -> bitmask u64 words. One thread per word (64 ints).
// ---------------------------------------------------------------------------
__global__ __launch_bounds__(256)
void maskbits_kernel(const int* __restrict__ mask, unsigned long long* __restrict__ mb)
{
    const int w = blockIdx.x * 256 + threadIdx.x;   // 65536 words
    const int* p = mask + (size_t)w * 64;
    unsigned long long bits = 0;
#pragma unroll
    for (int i = 0; i < 16; ++i) {
        int4 v = *(const int4*)(p + i * 4);
        bits |= (unsigned long long)(v.x != 0) << (i * 4 + 0);
        bits |= (unsigned long long)(v.y != 0) << (i * 4 + 1);
        bits |= (unsigned long long)(v.z != 0) << (i * 4 + 2);
        bits |= (unsigned long long)(v.w != 0) << (i * 4 + 3);
    }
    mb[w] = bits;
}

// ---------------------------------------------------------------------------
// Split-bf16 MFMA GEMM body (projections / out-proj).
// ---------------------------------------------------------------------------
template<int ASRC, int EPI>
__device__ __forceinline__ void gemm_body(
    const float* __restrict__ Af,
    const unsigned short* __restrict__ Ah_g, const unsigned short* __restrict__ Al_g,
    const unsigned short* __restrict__ Bh_g, const unsigned short* __restrict__ Bl_g,
    const float* __restrict__ bias,
    float* __restrict__ Yf, unsigned short* __restrict__ Yh, unsigned short* __restrict__ Yl,
    unsigned short* As_h, unsigned short* As_l, unsigned short* Bs_h, unsigned short* Bs_l,
    int m0, int n0)
{
    const int tid = threadIdx.x, lane = tid & 63, wid = tid >> 6;
    const int wm = (wid >> 1) * 64, wn = (wid & 1) * 64;
    f32x4 zero4 = {0.f, 0.f, 0.f, 0.f};
    f32x4 acc[4][4];
#pragma unroll
    for (int a = 0; a < 4; ++a)
#pragma unroll
        for (int b = 0; b < 4; ++b) acc[a][b] = zero4;

    for (int kt = 0; kt < 1024; kt += 64) {
        __syncthreads();
        if (ASRC == 0) {
#pragma unroll
            for (int i = 0; i < 8; ++i) {
                int c = tid + 256 * i; int r = c >> 4, c4 = c & 15;
                f32x4 v = *(const f32x4*)(Af + (size_t)(m0 + r) * 1024 + kt + c4 * 4);
                unsigned short h0 = f2bf(v.x), h1 = f2bf(v.y), h2 = f2bf(v.z), h3 = f2bf(v.w);
                unsigned short l0 = f2bf(v.x - bf2f(h0)), l1 = f2bf(v.y - bf2f(h1));
                unsigned short l2 = f2bf(v.z - bf2f(h2)), l3 = f2bf(v.w - bf2f(h3));
                int off = r * 64 + (((c4 >> 1) ^ (r & 7)) * 8) + (c4 & 1) * 4;
                *(s4v*)&As_h[off] = (s4v){(short)h0, (short)h1, (short)h2, (short)h3};
                *(s4v*)&As_l[off] = (s4v){(short)l0, (short)l1, (short)l2, (short)l3};
            }
        } else {
#pragma unroll
            for (int i = 0; i < 4; ++i) {
                int c = tid + 256 * i; int r = c >> 3, cc = c & 7;
                int off = r * 64 + ((cc ^ (r & 7)) * 8);
                *(bf8*)&As_h[off] = *(const bf8*)(Ah_g + (size_t)(m0 + r) * 1024 + kt + cc * 8);
                *(bf8*)&As_l[off] = *(const bf8*)(Al_g + (size_t)(m0 + r) * 1024 + kt + cc * 8);
            }
        }
#pragma unroll
        for (int i = 0; i < 4; ++i) {
            int c = tid + 256 * i; int r = c >> 3, cc = c & 7;
            int off = r * 64 + ((cc ^ (r & 7)) * 8);
            *(bf8*)&Bs_h[off] = *(const bf8*)(Bh_g + (size_t)(n0 + r) * 1024 + kt + cc * 8);
            *(bf8*)&Bs_l[off] = *(const bf8*)(Bl_g + (size_t)(n0 + r) * 1024 + kt + cc * 8);
        }
        __syncthreads();
#pragma unroll
        for (int ks = 0; ks < 2; ++ks) {
            bf8 ah[4], al[4], bh[4], bl[4];
#pragma unroll
            for (int f = 0; f < 4; ++f) {
                int ra = wm + f * 16 + (lane & 15);
                int ca = (ks * 4 + (lane >> 4)) ^ (ra & 7);
                ah[f] = *(const bf8*)&As_h[ra * 64 + ca * 8];
                al[f] = *(const bf8*)&As_l[ra * 64 + ca * 8];
                int rb = wn + f * 16 + (lane & 15);
                int cb = (ks * 4 + (lane >> 4)) ^ (rb & 7);
                bh[f] = *(const bf8*)&Bs_h[rb * 64 + cb * 8];
                bl[f] = *(const bf8*)&Bs_l[rb * 64 + cb * 8];
            }
#pragma unroll
            for (int fi = 0; fi < 4; ++fi)
#pragma unroll
                for (int fj = 0; fj < 4; ++fj) {
                    acc[fi][fj] = MFMA(ah[fi], bh[fj], acc[fi][fj]);
                    acc[fi][fj] = MFMA(al[fi], bh[fj], acc[fi][fj]);
                    acc[fi][fj] = MFMA(ah[fi], bl[fj], acc[fi][fj]);
                }
        }
    }
    // epilogue: C/D layout (m89): col = lane&15, row = (lane>>4)*4 + reg
#pragma unroll
    for (int fi = 0; fi < 4; ++fi)
#pragma unroll
        for (int fj = 0; fj < 4; ++fj)
#pragma unroll
            for (int rg = 0; rg < 4; ++rg) {
                int m = m0 + wm + fi * 16 + ((lane >> 4) << 2) + rg;
                int n = n0 + wn + fj * 16 + (lane & 15);
                float val = acc[fi][fj][rg] + bias[n];
                if (EPI == 0) {
                    int b = m >> 10, s = m & 1023, h = n >> 6, d = n & 63;
                    size_t o = (((size_t)(b * 16 + h)) * 1024 + s) * 64 + d;
                    unsigned short hv = f2bf(val);
                    unsigned short lv = f2bf(val - bf2f(hv));
                    Yh[o] = hv; Yl[o] = lv;
                } else {
                    Yf[(size_t)m * 1024 + n] = val;
                }
            }
}

__global__ __launch_bounds__(256, 2)
void proj_qkv_kernel(const float* __restrict__ q_in, const float* __restrict__ k_in,
                     const float* __restrict__ v_in,
                     const unsigned short* __restrict__ wt_hi, const unsigned short* __restrict__ wt_lo,
                     const float* __restrict__ bq, const float* __restrict__ bk,
                     const float* __restrict__ bv,
                     unsigned short* qh_hi, unsigned short* qh_lo,
                     unsigned short* kh_hi, unsigned short* kh_lo,
                     unsigned short* vh_hi, unsigned short* vh_lo)
{
    __shared__ __align__(16) unsigned short As_h[128 * 64], As_l[128 * 64];
    __shared__ __align__(16) unsigned short Bs_h[128 * 64], Bs_l[128 * 64];
    const int z = blockIdx.z;
    const float* X = z == 0 ? q_in : (z == 1 ? k_in : v_in);
    const float* bias = z == 0 ? bq : (z == 1 ? bk : bv);
    unsigned short* Yh = z == 0 ? qh_hi : (z == 1 ? kh_hi : vh_hi);
    unsigned short* Yl = z == 0 ? qh_lo : (z == 1 ? kh_lo : vh_lo);
    gemm_body<0, 0>(X, nullptr, nullptr,
                    wt_hi + (size_t)z * 1048576, wt_lo + (size_t)z * 1048576,
                    bias, nullptr, Yh, Yl, As_h, As_l, Bs_h, Bs_l,
                    blockIdx.x * 128, blockIdx.y * 128);
}

__global__ __launch_bounds__(256, 2)
void outproj_kernel(const unsigned short* __restrict__ ctx_hi, const unsigned short* __restrict__ ctx_lo,
                    const unsigned short* __restrict__ wo_hi, const unsigned short* __restrict__ wo_lo,
                    const float* __restrict__ bo, float* __restrict__ out)
{
    __shared__ __align__(16) unsigned short As_h[128 * 64], As_l[128 * 64];
    __shared__ __align__(16) unsigned short Bs_h[128 * 64], Bs_l[128 * 64];
    gemm_body<1, 1>(nullptr, ctx_hi, ctx_lo, wo_hi, wo_lo, bo, out, nullptr, nullptr,
                    As_h, As_l, Bs_h, Bs_l, blockIdx.x * 128, blockIdx.y * 128);
}

// ---------------------------------------------------------------------------
// V transpose: vh[bh][s][d] (ushort) -> vt[bh][d][s]. z: 0=hi,1=lo buffers.
// ---------------------------------------------------------------------------
__global__ __launch_bounds__(256, 4)
void vtrans_kernel(const unsigned short* __restrict__ vh_hi, const unsigned short* __restrict__ vh_lo,
                   unsigned short* __restrict__ vt_hi, unsigned short* __restrict__ vt_lo)
{
    __shared__ unsigned short T[64][72];
    const unsigned short* src = blockIdx.z ? vh_lo : vh_hi;
    unsigned short* dst = blockIdx.z ? vt_lo : vt_hi;
    const int st = blockIdx.x * 64, bh = blockIdx.y, tid = threadIdx.x;
#pragma unroll
    for (int i = 0; i < 4; ++i) {
        int c = tid + 256 * i; int r = c >> 4, d4 = c & 15;
        s4v v = *(const s4v*)(src + ((size_t)bh * 1024 + st + r) * 64 + d4 * 4);
        T[r][d4 * 4 + 0] = (unsigned short)v.x; T[r][d4 * 4 + 1] = (unsigned short)v.y;
        T[r][d4 * 4 + 2] = (unsigned short)v.z; T[r][d4 * 4 + 3] = (unsigned short)v.w;
    }
    __syncthreads();
#pragma unroll
    for (int i = 0; i < 4; ++i) {
        int c = tid + 256 * i; int r = c >> 4, s4_ = c & 15;  // r = d row
        s4v o = {(short)T[s4_ * 4 + 0][r], (short)T[s4_ * 4 + 1][r],
                 (short)T[s4_ * 4 + 2][r], (short)T[s4_ * 4 + 3][r]};
        *(s4v*)(dst + ((size_t)bh * 64 + r) * 1024 + st + s4_ * 4) = o;
    }
}

// ---------------------------------------------------------------------------
// Fused attention: per block 128 i-rows x one head.
// Grid is (x=head, y=i-block) so all 8 i-blocks of a head land on ONE XCD
// (flat = head + 64*ib -> XCD = head%8): K/V panels stay L2-resident across
// both passes. attn/ctx stores are nontemporal (streaming; keep L2 for K/V).
// ---------------------------------------------------------------------------
__global__ __launch_bounds__(256, 2)
void attn_fused_kernel(const unsigned short* __restrict__ qh_hi, const unsigned short* __restrict__ qh_lo,
                       const unsigned short* __restrict__ kh_hi, const unsigned short* __restrict__ kh_lo,
                       const unsigned short* __restrict__ vt_hi, const unsigned short* __restrict__ vt_lo,
                       const float* __restrict__ emb, const unsigned long long* __restrict__ mb,
                       float* __restrict__ attn,
                       unsigned short* __restrict__ ctx_hi, unsigned short* __restrict__ ctx_lo)
{
    __shared__ __align__(16) unsigned short Sh[128 * 64], Sl[128 * 64];  // Q then K tiles
    __shared__ __align__(16) unsigned short Pr[128 * PRELW];
    __shared__ float Sm[2][128], Ss[2][128], SmF[128], SsF[128];
    const int tid = threadIdx.x, lane = tid & 63, wid = tid >> 6;
    const int wi = wid >> 1, wj = wid & 1;
    const int g = lane >> 4, li = lane & 15;
    const int bh = blockIdx.x, i0 = blockIdx.y * 128, b = bh >> 4;
    const f32x4 zero4 = {0.f, 0.f, 0.f, 0.f};

    // ---- stage Q tile (swizzled rows = i) ----
    const unsigned short* qbh = qh_hi + ((size_t)bh * 1024 + i0) * 64;
    const unsigned short* qbl = qh_lo + ((size_t)bh * 1024 + i0) * 64;
#pragma unroll
    for (int i = 0; i < 4; ++i) {
        int c = tid + 256 * i; int r = c >> 3, cc = c & 7;
        int off = r * 64 + ((cc ^ (r & 7)) * 8);
        *(bf8*)&Sh[off] = *(const bf8*)(qbh + r * 64 + cc * 8);
        *(bf8*)&Sl[off] = *(const bf8*)(qbl + r * 64 + cc * 8);
    }
    __syncthreads();

    // ---- Q fragments to registers ----
    bf8 qfh[4][2], qfl[4][2];
#pragma unroll
    for (int fi = 0; fi < 4; ++fi)
#pragma unroll
        for (int ks = 0; ks < 2; ++ks) {
            int rb = wi * 64 + fi * 16 + li;
            int cb = (ks * 4 + g) ^ (rb & 7);
            qfh[fi][ks] = *(const bf8*)&Sh[rb * 64 + cb * 8];
            qfl[fi][ks] = *(const bf8*)&Sl[rb * 64 + cb * 8];
        }

    // ---- rel-bias Pr[i][r] = q_hi[i]. emb[r] via MFMA, stored bf16 ----
    for (int t = wid; t < 72; t += 4) {       // 8 i-tiles x 9 r-tiles
        const int it = t / 9, rt = t % 9;
        f32x4 pc = zero4;
#pragma unroll
        for (int ks = 0; ks < 2; ++ks) {
            int ra = it * 16 + li;
            int ca = (ks * 4 + g) ^ (ra & 7);
            bf8 aq = *(const bf8*)&Sh[ra * 64 + ca * 8];
            int er = rt * 16 + li; if (er > 128) er = 128;   // clamp OOB rows
            const float* ep = emb + (size_t)er * 64 + ks * 32 + g * 8;
            f32x4 e0 = *(const f32x4*)ep;
            f32x4 e1 = *(const f32x4*)(ep + 4);
            bf8 be = {(short)f2bf(e0.x), (short)f2bf(e0.y), (short)f2bf(e0.z), (short)f2bf(e0.w),
                      (short)f2bf(e1.x), (short)f2bf(e1.y), (short)f2bf(e1.z), (short)f2bf(e1.w)};
            pc = MFMA(aq, be, pc);
        }
        const int rcol = rt * 16 + li;
        if (rcol < RR) {
#pragma unroll
            for (int rg = 0; rg < 4; ++rg)
                Pr[(it * 16 + g * 4 + rg) * PRELW + rcol] = f2bf(pc[rg]);
        }
    }

    float rm[4], rs[4];
#pragma unroll
    for (int i = 0; i < 4; ++i) { rm[i] = -3.0e38f; rs[i] = 0.f; }

    // ================= PASS 1: stats only =================
    for (int jt = 0; jt < 8; ++jt) {
        __syncthreads();   // Pr writes done (jt=0); prior frag reads done (jt>0)
        const unsigned short* kbh = kh_hi + ((size_t)bh * 1024 + jt * 128) * 64;
        const unsigned short* kbl = kh_lo + ((size_t)bh * 1024 + jt * 128) * 64;
#pragma unroll
        for (int i = 0; i < 4; ++i) {
            int c = tid + 256 * i; int r = c >> 3, cc = c & 7;
            int off = r * 64 + ((cc ^ (r & 7)) * 8);
            *(bf8*)&Sh[off] = *(const bf8*)(kbh + r * 64 + cc * 8);
            *(bf8*)&Sl[off] = *(const bf8*)(kbl + r * 64 + cc * 8);
        }
        __syncthreads();
        f32x4 acc[4][4];  // [fj][fi]
#pragma unroll
        for (int a = 0; a < 4; ++a)
#pragma unroll
            for (int c = 0; c < 4; ++c) acc[a][c] = zero4;
#pragma unroll
        for (int ks = 0; ks < 2; ++ks) {
            bf8 kfh[4], kfl[4];
#pragma unroll
            for (int fj = 0; fj < 4; ++fj) {
                int ra = wj * 64 + fj * 16 + li;
                int ca = (ks * 4 + g) ^ (ra & 7);
                kfh[fj] = *(const bf8*)&Sh[ra * 64 + ca * 8];
                kfl[fj] = *(const bf8*)&Sl[ra * 64 + ca * 8];
            }
#pragma unroll
            for (int fj = 0; fj < 4; ++fj)
#pragma unroll
                for (int fi = 0; fi < 4; ++fi) {
                    acc[fj][fi] = MFMA(kfh[fj], qfh[fi][ks], acc[fj][fi]);
                    acc[fj][fi] = MFMA(kfl[fj], qfh[fi][ks], acc[fj][fi]);
                    acc[fj][fi] = MFMA(kfh[fj], qfl[fi][ks], acc[fj][fi]);
                }
        }
#pragma unroll
        for (int fi = 0; fi < 4; ++fi) {
            const int rowL = wi * 64 + fi * 16 + li;
            const int ii = i0 + rowL;
            const unsigned long long mw = mb[((size_t)b * 1024 + ii) * 16 + jt * 2 + wj];
            float p16[4][4];
            float tmax = -3.0e38f;
#pragma unroll
            for (int fj = 0; fj < 4; ++fj)
#pragma unroll
                for (int rg = 0; rg < 4; ++rg) {
                    int jloc = fj * 16 + g * 4 + rg;
                    int jj = jt * 128 + wj * 64 + jloc;
                    int dd = ii - jj; dd = dd < -64 ? -64 : (dd > 64 ? 64 : dd);
                    float s = acc[fj][fi][rg] * 0.125f + bf2f(Pr[rowL * PRELW + dd + 64]);
                    if (!((mw >> jloc) & 1ull)) s = -1.0e30f;
                    p16[fj][rg] = s;
                    tmax = fmaxf(tmax, s);
                }
            tmax = fmaxf(tmax, __shfl_xor(tmax, 16, 64));
            tmax = fmaxf(tmax, __shfl_xor(tmax, 32, 64));
            float nm = fmaxf(rm[fi], tmax);
            float ps = 0.f;
#pragma unroll
            for (int fj = 0; fj < 4; ++fj)
#pragma unroll
                for (int rg = 0; rg < 4; ++rg) ps += __expf(p16[fj][rg] - nm);
            ps += __shfl_xor(ps, 16, 64);
            ps += __shfl_xor(ps, 32, 64);
            rs[fi] = rs[fi] * __expf(rm[fi] - nm) + ps;
            rm[fi] = nm;
        }
    }
    // combine the two j-half waves per i-row
#pragma unroll
    for (int fi = 0; fi < 4; ++fi) {
        if (lane < 16) {
            Sm[wj][wi * 64 + fi * 16 + li] = rm[fi];
            Ss[wj][wi * 64 + fi * 16 + li] = rs[fi];
        }
    }
    __syncthreads();
    if (tid < 128) {
        float m0_ = Sm[0][tid], m1_ = Sm[1][tid];
        float mmx = fmaxf(m0_, m1_);
        SmF[tid] = mmx;
        SsF[tid] = Ss[0][tid] * __expf(m0_ - mmx) + Ss[1][tid] * __expf(m1_ - mmx);
    }
    __syncthreads();
    float mm4[4], iv4[4];
#pragma unroll
    for (int fi = 0; fi < 4; ++fi) {
        mm4[fi] = SmF[wi * 64 + fi * 16 + li];
        iv4[fi] = 1.f / SsF[wi * 64 + fi * 16 + li];
    }

    f32x4 ctx_acc[4][4];  // [fi][fd]
#pragma unroll
    for (int a = 0; a < 4; ++a)
#pragma unroll
        for (int c = 0; c < 4; ++c) ctx_acc[a][c] = zero4;

    // ================= PASS 2: weights write + PV =================
    for (int jt = 0; jt < 8; ++jt) {
        __syncthreads();
        const unsigned short* kbh = kh_hi + ((size_t)bh * 1024 + jt * 128) * 64;
        const unsigned short* kbl = kh_lo + ((size_t)bh * 1024 + jt * 128) * 64;
#pragma unroll
        for (int i = 0; i < 4; ++i) {
            int c = tid + 256 * i; int r = c >> 3, cc = c & 7;
            int off = r * 64 + ((cc ^ (r & 7)) * 8);
            *(bf8*)&Sh[off] = *(const bf8*)(kbh + r * 64 + cc * 8);
            *(bf8*)&Sl[off] = *(const bf8*)(kbl + r * 64 + cc * 8);
        }
        __syncthreads();
        f32x4 acc[4][4];  // identical recompute -> identical s values
#pragma unroll
        for (int a = 0; a < 4; ++a)
#pragma unroll
            for (int c = 0; c < 4; ++c) acc[a][c] = zero4;
#pragma unroll
        for (int ks = 0; ks < 2; ++ks) {
            bf8 kfh[4], kfl[4];
#pragma unroll
            for (int fj = 0; fj < 4; ++fj) {
                int ra = wj * 64 + fj * 16 + li;
                int ca = (ks * 4 + g) ^ (ra & 7);
                kfh[fj] = *(const bf8*)&Sh[ra * 64 + ca * 8];
                kfl[fj] = *(const bf8*)&Sl[ra * 64 + ca * 8];
            }
#pragma unroll
            for (int fj = 0; fj < 4; ++fj)
#pragma unroll
                for (int fi = 0; fi < 4; ++fi) {
                    acc[fj][fi] = MFMA(kfh[fj], qfh[fi][ks], acc[fj][fi]);
                    acc[fj][fi] = MFMA(kfl[fj], qfh[fi][ks], acc[fj][fi]);
                    acc[fj][fi] = MFMA(kfh[fj], qfl[fi][ks], acc[fj][fi]);
                }
        }
        // per 32-j chunk: V frags from global vt, p+store+pack, shfl, PV MFMA
#pragma unroll
        for (int c = 0; c < 2; ++c) {
            bf8 vfh[4], vfl[4];
#pragma unroll
            for (int fd = 0; fd < 4; ++fd) {
                size_t vb = (size_t)bh * 65536 + (size_t)(fd * 16 + li) * 1024
                          + jt * 128 + wj * 64 + c * 32 + g * 8;
                vfh[fd] = *(const bf8*)(vt_hi + vb);
                vfl[fd] = *(const bf8*)(vt_lo + vb);
            }
#pragma unroll
            for (int fi = 0; fi < 4; ++fi) {
                const int rowL = wi * 64 + fi * 16 + li;
                const int ii = i0 + rowL;
                const unsigned long long mw = mb[((size_t)b * 1024 + ii) * 16 + jt * 2 + wj];
                const float mmf = mm4[fi], ivf = iv4[fi];
                float* arow = attn + ((size_t)bh * 1024 + ii) * 1024 + jt * 128 + wj * 64 + g * 4;
                unsigned wh[2][2], wl[2][2];
#pragma unroll
                for (int t = 0; t < 2; ++t) {
                    const int fj = c * 2 + t;
                    f32x4 pv;
#pragma unroll
                    for (int rg = 0; rg < 4; ++rg) {
                        int jloc = fj * 16 + g * 4 + rg;
                        int jj = jt * 128 + wj * 64 + jloc;
                        int dd = ii - jj; dd = dd < -64 ? -64 : (dd > 64 ? 64 : dd);
                        float s = acc[fj][fi][rg] * 0.125f + bf2f(Pr[rowL * PRELW + dd + 64]);
                        if (!((mw >> jloc) & 1ull)) s = -1.0e30f;
                        pv[rg] = __expf(s - mmf) * ivf;
                    }
                    __builtin_nontemporal_store(pv, (f32x4*)(arow + fj * 16));  // final weights
                    unsigned short h0 = f2bf(pv.x), h1 = f2bf(pv.y), h2 = f2bf(pv.z), h3 = f2bf(pv.w);
                    wh[t][0] = (unsigned)h0 | ((unsigned)h1 << 16);
                    wh[t][1] = (unsigned)h2 | ((unsigned)h3 << 16);
                    unsigned short l0 = f2bf(pv.x - bf2f(h0)), l1 = f2bf(pv.y - bf2f(h1));
                    unsigned short l2 = f2bf(pv.z - bf2f(h2)), l3 = f2bf(pv.w - bf2f(h3));
                    wl[t][0] = (unsigned)l0 | ((unsigned)l1 << 16);
                    wl[t][1] = (unsigned)l2 | ((unsigned)l3 << 16);
                }
                // redistribute: dest lane g needs tile (g>>1), source groups (g&1)*2, +1
                const int src0 = ((g & 1) * 2) * 16 + li;
                const int src1 = src0 + 16;
                const bool hiT = (g >> 1) & 1;
                int x0A = __shfl((int)wh[0][0], src0, 64), x0B = __shfl((int)wh[1][0], src0, 64);
                int x1A = __shfl((int)wh[0][1], src0, 64), x1B = __shfl((int)wh[1][1], src0, 64);
                int x2A = __shfl((int)wh[0][0], src1, 64), x2B = __shfl((int)wh[1][0], src1, 64);
                int x3A = __shfl((int)wh[0][1], src1, 64), x3B = __shfl((int)wh[1][1], src1, 64);
                i32x4 awh = {hiT ? x0B : x0A, hiT ? x1B : x1A, hiT ? x2B : x2A, hiT ? x3B : x3A};
                bf8 pah = *(bf8*)&awh;
                int y0A = __shfl((int)wl[0][0], src0, 64), y0B = __shfl((int)wl[1][0], src0, 64);
                int y1A = __shfl((int)wl[0][1], src0, 64), y1B = __shfl((int)wl[1][1], src0, 64);
                int y2A = __shfl((int)wl[0][0], src1, 64), y2B = __shfl((int)wl[1][0], src1, 64);
                int y3A = __shfl((int)wl[0][1], src1, 64), y3B = __shfl((int)wl[1][1], src1, 64);
                i32x4 awl = {hiT ? y0B : y0A, hiT ? y1B : y1A, hiT ? y2B : y2A, hiT ? y3B : y3A};
                bf8 pal = *(bf8*)&awl;
#pragma unroll
                for (int fd = 0; fd < 4; ++fd) {
                    ctx_acc[fi][fd] = MFMA(pah, vfh[fd], ctx_acc[fi][fd]);
                    ctx_acc[fi][fd] = MFMA(pal, vfh[fd], ctx_acc[fi][fd]);
                    ctx_acc[fi][fd] = MFMA(pah, vfl[fd], ctx_acc[fi][fd]);
                }
            }
        }
    }

    // ---- reduce ctx_acc across the wj wave pair (Sh/Sl reused as scratch) ----
    __syncthreads();                         // all waves done reading Sh/Sl
    float* red = (wi == 0) ? (float*)Sh : (float*)Sl;   // 4096 floats each
    if (wj == 1) {
#pragma unroll
        for (int fi = 0; fi < 4; ++fi)
#pragma unroll
            for (int fd = 0; fd < 4; ++fd)
#pragma unroll
                for (int rg = 0; rg < 4; ++rg) {
                    int idx = (fi * 4 + fd) * 4 + rg;
                    red[lane * 64 + ((idx + lane) & 63)] = ctx_acc[fi][fd][rg];
                }
    }
    __syncthreads();
    if (wj == 0) {
        const int b_ = bh >> 4, h = bh & 15;
#pragma unroll
        for (int fi = 0; fi < 4; ++fi)
#pragma unroll
            for (int fd = 0; fd < 4; ++fd)
#pragma unroll
                for (int rg = 0; rg < 4; ++rg) {
                    int idx = (fi * 4 + fd) * 4 + rg;
                    float val = ctx_acc[fi][fd][rg] + red[lane * 64 + ((idx + lane) & 63)];
                    int ii = i0 + wi * 64 + fi * 16 + g * 4 + rg;
                    int d = fd * 16 + li;
                    size_t o = ((size_t)b_ * 1024 + ii) * 1024 + h * 64 + d;
                    unsigned short hv = f2bf(val);
                    unsigned short lv = f2bf(val - bf2f(hv));
                    __builtin_nontemporal_store(hv, &ctx_hi[o]);
                    __builtin_nontemporal_store(lv, &ctx_lo[o]);
                }
    }
}

extern "C" void kernel_launch(void* const* d_in, const int* in_sizes, int n_in,
                              void* d_out, int out_size, void* d_ws, size_t ws_size,
                              hipStream_t stream)
{
    const float* query = (const float*)d_in[0];
    const float* key_  = (const float*)d_in[1];
    const float* value = (const float*)d_in[2];
    const int*   mask  = (const int*)d_in[3];
    const float* Wq = (const float*)d_in[4];
    const float* bq = (const float*)d_in[5];
    const float* Wk = (const float*)d_in[6];
    const float* bk = (const float*)d_in[7];
    const float* Wv = (const float*)d_in[8];
    const float* bv = (const float*)d_in[9];
    const float* Wo = (const float*)d_in[10];
    const float* bo = (const float*)d_in[11];
    const float* emb = (const float*)d_in[12];

    // workspace: 80.0 MB (<= 84.1 MB proven in earlier rounds)
    unsigned short* wt_hi = (unsigned short*)d_ws;           // [4][1024][1024]
    unsigned short* wt_lo = wt_hi + (size_t)4 * 1048576;
    unsigned short* qh_hi = wt_lo + (size_t)4 * 1048576;     // [64][1024][64]
    unsigned short* qh_lo = qh_hi + 4194304;
    unsigned short* kh_hi = qh_lo + 4194304;
    unsigned short* kh_lo = kh_hi + 4194304;
    unsigned short* vt_hi = kh_lo + 4194304;                 // [64][64][1024]
    unsigned short* vt_lo = vt_hi + 4194304;
    unsigned short* ctx_hi = vt_lo + 4194304;                // [4][1024][1024]
    unsigned short* ctx_lo = ctx_hi + 4194304;
    // bitmask overlays the (dead-after-projection) Wq^T-hi region:
    unsigned long long* mb = (unsigned long long*)d_ws;      // [65536] = 512 KB
    // v-heads scratch lives in the out region (dead after vtrans; out written last):
    unsigned short* vh_hi = (unsigned short*)d_out;          // 16 MB region
    unsigned short* vh_lo = vh_hi + 4194304;

    float* out  = (float*)d_out;
    float* attn = (float*)d_out + 4194304;

    dim3 blk(256);
    wtrans_kernel<<<dim3(16, 16, 4), blk, 0, stream>>>(Wq, Wk, Wv, Wo, wt_hi, wt_lo);
    proj_qkv_kernel<<<dim3(32, 8, 3), blk, 0, stream>>>(query, key_, value, wt_hi, wt_lo,
                                                        bq, bk, bv, qh_hi, qh_lo,
                                                        kh_hi, kh_lo, vh_hi, vh_lo);
    maskbits_kernel<<<dim3(256), blk, 0, stream>>>(mask, mb);   // after proj (mb overlays Wq^T)
    vtrans_kernel<<<dim3(16, 64, 2), blk, 0, stream>>>(vh_hi, vh_lo, vt_hi, vt_lo);
    attn_fused_kernel<<<dim3(64, 8), blk, 0, stream>>>(qh_hi, qh_lo, kh_hi, kh_lo,
                                                       vt_hi, vt_lo, emb, mb,
                                                       attn, ctx_hi, ctx_lo);
    outproj_kernel<<<dim3(32, 8), blk, 0, stream>>>(ctx_hi, ctx_lo,
                                                    wt_hi + (size_t)3 * 1048576,
                                                    wt_lo + (size_t)3 * 1048576, bo, out);
}